// Round 5
// baseline (1255.041 us; speedup 1.0000x reference)
//
#include <hip/hip_runtime.h>

// ---------------- CSR build ----------------
__global__ void k_hist(const int* __restrict__ dst, int* __restrict__ cnt, int E) {
    int e = blockIdx.x * 256 + threadIdx.x;
    if (e < E) atomicAdd(&cnt[dst[e]], 1);
}

__global__ void k_blocksum(const int* __restrict__ cnt, int* __restrict__ bsums, int n) {
    int base = blockIdx.x * 1024;
    int t = threadIdx.x;
    int s = 0;
    for (int j = t; j < 1024; j += 256) { int i = base + j; if (i < n) s += cnt[i]; }
    __shared__ int red[256];
    red[t] = s; __syncthreads();
    for (int off = 128; off > 0; off >>= 1) { if (t < off) red[t] += red[t + off]; __syncthreads(); }
    if (t == 0) bsums[blockIdx.x] = red[0];
}

__global__ void k_scan_bsums(int* __restrict__ bsums, int nb) {
    if (threadIdx.x == 0) {
        int run = 0;
        for (int i = 0; i < nb; i++) { int v = bsums[i]; bsums[i] = run; run += v; }
    }
}

__global__ void k_scan_final(int* __restrict__ cnt, const int* __restrict__ bsums,
                             int* __restrict__ rowptr, float* __restrict__ dinv, int n, int E) {
    int base = blockIdx.x * 1024;
    int t = threadIdx.x;
    int i0 = base + t * 4;
    int v[4]; int s = 0;
    for (int j = 0; j < 4; j++) { int i = i0 + j; v[j] = (i < n) ? cnt[i] : 0; s += v[j]; }
    __shared__ int sc[256];
    sc[t] = s; __syncthreads();
    int acc = s;
    for (int off = 1; off < 256; off <<= 1) {
        int add = (t >= off) ? sc[t - off] : 0;
        __syncthreads();
        acc += add; sc[t] = acc;
        __syncthreads();
    }
    int run = acc - s + bsums[blockIdx.x];
    for (int j = 0; j < 4; j++) {
        int i = i0 + j;
        if (i < n) {
            rowptr[i] = run;
            dinv[i] = rsqrtf((float)(v[j] + 1));
            cnt[i] = run;   // cursor for scatter
            run += v[j];
        }
    }
    if (blockIdx.x == 0 && t == 0) rowptr[n] = E;
}

__global__ void k_scatter(const int* __restrict__ ei, int* __restrict__ cursor,
                          const float* __restrict__ dinv,
                          int* __restrict__ csr, float* __restrict__ wnorm, int E) {
    int e = blockIdx.x * 256 + threadIdx.x;
    if (e < E) {
        int s = ei[e], d = ei[E + e];
        int pos = atomicAdd(&cursor[d], 1);
        csr[pos] = s;
        wnorm[pos] = dinv[s] * dinv[d];
    }
}

// ---------------- GEMM1: xw1 = x @ W1 -> C[node][0..63] (f32, stride 128) ----------------
__global__ __launch_bounds__(256) void k_gemm1(const float* __restrict__ x,
                                               const float* __restrict__ W1,
                                               float* __restrict__ C, int n) {
    int w = threadIdx.x >> 6, l = threadIdx.x & 63;
    int n0 = blockIdx.x * 8 + w * 2, n1 = n0 + 1;
    __shared__ float xs[8][256];
    if (n0 < n) {
        float4 u = ((const float4*)(x + (size_t)n0 * 256))[l];
        xs[w * 2][l * 4 + 0] = u.x; xs[w * 2][l * 4 + 1] = u.y;
        xs[w * 2][l * 4 + 2] = u.z; xs[w * 2][l * 4 + 3] = u.w;
    }
    if (n1 < n) {
        float4 u = ((const float4*)(x + (size_t)n1 * 256))[l];
        xs[w * 2 + 1][l * 4 + 0] = u.x; xs[w * 2 + 1][l * 4 + 1] = u.y;
        xs[w * 2 + 1][l * 4 + 2] = u.z; xs[w * 2 + 1][l * 4 + 3] = u.w;
    }
    __syncthreads();
    if (n0 >= n) return;
    float a0 = 0.f, a1 = 0.f;
    #pragma unroll 8
    for (int k = 0; k < 256; k++) {
        float wv = W1[k * 64 + l];
        a0 += xs[w * 2][k] * wv;
        a1 += xs[w * 2 + 1][k] * wv;
    }
    C[(size_t)n0 * 128 + l] = a0;
    if (n1 < n) C[(size_t)n1 * 128 + l] = a1;
}

// ---------------- GCN1 aggregate: h1 = relu(Anorm*xw1 + b1) -> B ----------------
__global__ __launch_bounds__(256) void k_agg1(const float* __restrict__ C,
                                              const int* __restrict__ csr,
                                              const int* __restrict__ rowptr,
                                              const float* __restrict__ wnorm,
                                              const float* __restrict__ dinv,
                                              const float* __restrict__ b1,
                                              float* __restrict__ B, int n) {
    int w = threadIdx.x >> 6, l = threadIdx.x & 63;
    int node = blockIdx.x * 4 + w;
    if (node >= n) return;
    float di = dinv[node];
    float acc = C[(size_t)node * 128 + l] * di * di;   // self loop
    int beg = rowptr[node], end = rowptr[node + 1];
    for (int e = beg; e < end; e++) {
        int s = csr[e];
        acc += C[(size_t)s * 128 + l] * wnorm[e];
    }
    acc += b1[l];
    B[(size_t)node * 64 + l] = fmaxf(acc, 0.f);
}

// ---------------- lin_kv: k,v -> C interleaved ----------------
__global__ __launch_bounds__(256) void k_lin_kv(const float* __restrict__ B,
                                                const float* __restrict__ Wk, const float* __restrict__ bk,
                                                const float* __restrict__ Wv, const float* __restrict__ bv,
                                                float* __restrict__ C, int n) {
    int w = threadIdx.x >> 6, l = threadIdx.x & 63;
    int n0 = blockIdx.x * 8 + w * 2, n1 = n0 + 1;
    __shared__ float hs[8][64];
    if (n0 < n) hs[w * 2][l] = B[(size_t)n0 * 64 + l];
    if (n1 < n) hs[w * 2 + 1][l] = B[(size_t)n1 * 64 + l];
    __syncthreads();
    if (n0 >= n) return;
    float k0 = 0, v0 = 0, k1 = 0, v1 = 0;
    #pragma unroll 4
    for (int kk = 0; kk < 64; kk++) {
        float h0 = hs[w * 2][kk], h1v = hs[w * 2 + 1][kk];
        float wk = Wk[kk * 64 + l]; k0 += h0 * wk; k1 += h1v * wk;
        float wv = Wv[kk * 64 + l]; v0 += h0 * wv; v1 += h1v * wv;
    }
    float bkl = bk[l], bvl = bv[l];
    C[(size_t)n0 * 128 + l]      = k0 + bkl;
    C[(size_t)n0 * 128 + 64 + l] = v0 + bvl;
    if (n1 < n) {
        C[(size_t)n1 * 128 + l]      = k1 + bkl;
        C[(size_t)n1 * 128 + 64 + l] = v1 + bvl;
    }
}

// ------- attention: warp/node; q & skip on the fly (Wq,Ws in LDS); h2 -> ws -------
__global__ __launch_bounds__(256) void k_attn(const float* __restrict__ B,
                                              const float* __restrict__ C,
                                              const int* __restrict__ csr,
                                              const int* __restrict__ rowptr,
                                              const float* __restrict__ Wq, const float* __restrict__ bq,
                                              const float* __restrict__ Ws, const float* __restrict__ bs,
                                              float* __restrict__ h2, int n) {
    __shared__ float2 wqs[64 * 64];
    __shared__ float2 bqs[64];
    int t = threadIdx.x;
    for (int i = t; i < 4096; i += 256)
        wqs[i] = make_float2(Wq[i], Ws[i]);
    if (t < 64) bqs[t] = make_float2(bq[t], bs[t]);
    __syncthreads();

    int w = t >> 6, l = t & 63;
    int node = blockIdx.x * 4 + w;
    if (node >= n) return;

    float hl = B[(size_t)node * 64 + l];
    float q = bqs[l].x, sk = bqs[l].y;
    #pragma unroll 8
    for (int kk = 0; kk < 64; kk++) {
        float hk = __shfl(hl, kk);
        float2 wv = wqs[kk * 64 + l];
        q += hk * wv.x;
        sk += hk * wv.y;
    }

    int beg = rowptr[node], end = rowptr[node + 1];
    float m = -1e30f, den = 0.f, acc = 0.f;
    for (int e = beg; e < end; e++) {
        int s = csr[e];
        float kl = C[(size_t)s * 128 + l];
        float vl = C[(size_t)s * 128 + 64 + l];
        float d = q * kl;
        #pragma unroll
        for (int off = 1; off < 64; off <<= 1) d += __shfl_xor(d, off);
        d *= 0.125f;
        float nm = fmaxf(m, d);
        float r = __expf(m - nm);
        float p = __expf(d - nm);
        den = den * r + p;
        acc = acc * r + p * vl;
        m = nm;
    }
    float outv = (den > 0.f) ? acc / den : 0.f;
    h2[(size_t)node * 64 + l] = outv + sk;
}

// ------- fused GCN2 aggregate + GEMM2: out = (Anorm*h2) @ W2 + b2 -------
// 16 nodes/block; agg kept in LDS only; reads h2 from ws -> no d_out read/write hazard.
__global__ __launch_bounds__(256) void k_agg2gemm2(const float* __restrict__ h2,
                                                   const int* __restrict__ csr,
                                                   const int* __restrict__ rowptr,
                                                   const float* __restrict__ wnorm,
                                                   const float* __restrict__ dinv,
                                                   const float* __restrict__ W2,
                                                   const float* __restrict__ b2,
                                                   float* __restrict__ out, int n) {
    __shared__ float ag[16][64];
    int t = threadIdx.x, w = t >> 6, l = t & 63;
    int base = blockIdx.x * 16;
    for (int i = w; i < 16; i += 4) {
        int node = base + i;
        float acc = 0.f;
        if (node < n) {
            float di = dinv[node];
            acc = h2[(size_t)node * 64 + l] * di * di;
            int beg = rowptr[node], end = rowptr[node + 1];
            for (int e = beg; e < end; e++) {
                int s = csr[e];
                acc += h2[(size_t)s * 64 + l] * wnorm[e];
            }
        }
        ag[i][l] = acc;
    }
    __syncthreads();
    float r[16];
    float bias = b2[t];
    #pragma unroll
    for (int i = 0; i < 16; i++) r[i] = bias;
    for (int k = 0; k < 64; k++) {
        float wv = W2[k * 256 + t];
        #pragma unroll
        for (int i = 0; i < 16; i++) r[i] += ag[i][k] * wv;
    }
    for (int i = 0; i < 16; i++) {
        int node = base + i;
        if (node < n) out[(size_t)node * 256 + t] = r[i];
    }
}

extern "C" void kernel_launch(void* const* d_in, const int* in_sizes, int n_in,
                              void* d_out, int out_size, void* d_ws, size_t ws_size,
                              hipStream_t stream) {
    const float* x  = (const float*)d_in[0];
    const int*   ei = (const int*)d_in[1];
    const float* W1 = (const float*)d_in[2];
    const float* b1 = (const float*)d_in[3];
    const float* Wq = (const float*)d_in[4];
    const float* bq = (const float*)d_in[5];
    const float* Wk = (const float*)d_in[6];
    const float* bk = (const float*)d_in[7];
    const float* Wv = (const float*)d_in[8];
    const float* bv = (const float*)d_in[9];
    const float* Ws = (const float*)d_in[10];
    const float* bs = (const float*)d_in[11];
    const float* W2 = (const float*)d_in[12];
    const float* b2 = (const float*)d_in[13];
    float* out = (float*)d_out;

    const int N = in_sizes[0] / 256;
    const int E = in_sizes[1] / 2;

    // d_out staging (f32 x N*256 elements): C = [N][128] (xw1 slot0, then k||v),
    // B = [N][64] h1. Both dead before k_agg2gemm2 rewrites out.
    float* C = (float*)d_out;
    float* B = (float*)d_out + (size_t)N * 128;

    // d_ws (~40 MB): CSR machinery + per-edge norm + h2
    char* p = (char*)d_ws;
    auto alloc = [&](size_t bytes) { char* r = p; p += (bytes + 255) & ~(size_t)255; return r; };
    int*   cnt    = (int*)alloc((size_t)N * 4);        // becomes scatter cursor
    int*   rowptr = (int*)alloc((size_t)(N + 1) * 4);
    int*   bsums  = (int*)alloc(1024);
    int*   csr    = (int*)alloc((size_t)E * 4);
    float* dinv   = (float*)alloc((size_t)N * 4);
    float* wnorm  = (float*)alloc((size_t)E * 4);
    float* h2     = (float*)alloc((size_t)N * 64 * 4);

    const int NB = (N + 1023) / 1024;

    hipMemsetAsync(cnt, 0, (size_t)N * 4, stream);
    k_hist<<<(E + 255) / 256, 256, 0, stream>>>(ei + E, cnt, E);
    k_blocksum<<<NB, 256, 0, stream>>>(cnt, bsums, N);
    k_scan_bsums<<<1, 64, 0, stream>>>(bsums, NB);
    k_scan_final<<<NB, 256, 0, stream>>>(cnt, bsums, rowptr, dinv, N, E);
    k_scatter<<<(E + 255) / 256, 256, 0, stream>>>(ei, cnt, dinv, csr, wnorm, E);

    k_gemm1<<<(N + 7) / 8, 256, 0, stream>>>(x, W1, C, N);
    k_agg1<<<(N + 3) / 4, 256, 0, stream>>>(C, csr, rowptr, wnorm, dinv, b1, B, N);
    k_lin_kv<<<(N + 7) / 8, 256, 0, stream>>>(B, Wk, bk, Wv, bv, C, N);
    k_attn<<<(N + 3) / 4, 256, 0, stream>>>(B, C, csr, rowptr, Wq, bq, Ws, bs, h2, N);
    k_agg2gemm2<<<(N + 15) / 16, 256, 0, stream>>>(h2, csr, rowptr, wnorm, dinv, W2, b2, out, N);
}

// Round 6
// 718.419 us; speedup vs baseline: 1.7469x; 1.7469x over previous
//
#include <hip/hip_runtime.h>

__device__ __forceinline__ float4 shfl_xor4(float4 v, int off) {
    return make_float4(__shfl_xor(v.x, off), __shfl_xor(v.y, off),
                       __shfl_xor(v.z, off), __shfl_xor(v.w, off));
}

// ---------------- CSR build ----------------
__global__ void k_hist(const int* __restrict__ dst, int* __restrict__ cnt, int E) {
    int e = blockIdx.x * 256 + threadIdx.x;
    if (e < E) atomicAdd(&cnt[dst[e]], 1);
}

__global__ void k_blocksum(const int* __restrict__ cnt, int* __restrict__ bsums, int n) {
    int base = blockIdx.x * 1024;
    int t = threadIdx.x;
    int s = 0;
    for (int j = t; j < 1024; j += 256) { int i = base + j; if (i < n) s += cnt[i]; }
    __shared__ int red[256];
    red[t] = s; __syncthreads();
    for (int off = 128; off > 0; off >>= 1) { if (t < off) red[t] += red[t + off]; __syncthreads(); }
    if (t == 0) bsums[blockIdx.x] = red[0];
}

__global__ void k_scan_bsums(int* __restrict__ bsums, int nb) {
    if (threadIdx.x == 0) {
        int run = 0;
        for (int i = 0; i < nb; i++) { int v = bsums[i]; bsums[i] = run; run += v; }
    }
}

__global__ void k_scan_final(int* __restrict__ cnt, const int* __restrict__ bsums,
                             int* __restrict__ rowptr, float* __restrict__ dinv, int n, int E) {
    int base = blockIdx.x * 1024;
    int t = threadIdx.x;
    int i0 = base + t * 4;
    int v[4]; int s = 0;
    for (int j = 0; j < 4; j++) { int i = i0 + j; v[j] = (i < n) ? cnt[i] : 0; s += v[j]; }
    __shared__ int sc[256];
    sc[t] = s; __syncthreads();
    int acc = s;
    for (int off = 1; off < 256; off <<= 1) {
        int add = (t >= off) ? sc[t - off] : 0;
        __syncthreads();
        acc += add; sc[t] = acc;
        __syncthreads();
    }
    int run = acc - s + bsums[blockIdx.x];
    for (int j = 0; j < 4; j++) {
        int i = i0 + j;
        if (i < n) {
            rowptr[i] = run;
            dinv[i] = rsqrtf((float)(v[j] + 1));
            cnt[i] = run;   // cursor for scatter
            run += v[j];
        }
    }
    if (blockIdx.x == 0 && t == 0) rowptr[n] = E;
}

__global__ void k_scatter(const int* __restrict__ ei, int* __restrict__ cursor,
                          const float* __restrict__ dinv,
                          int* __restrict__ csr, float* __restrict__ wnorm, int E) {
    int e = blockIdx.x * 256 + threadIdx.x;
    if (e < E) {
        int s = ei[e], d = ei[E + e];
        int pos = atomicAdd(&cursor[d], 1);
        csr[pos] = s;
        wnorm[pos] = dinv[s] * dinv[d];
    }
}

// ---------------- GEMM1: xw1 = x @ W1 -> C[node][0..63] (f32, stride 128) ----------------
__global__ __launch_bounds__(256) void k_gemm1(const float* __restrict__ x,
                                               const float* __restrict__ W1,
                                               float* __restrict__ C, int n) {
    int w = threadIdx.x >> 6, l = threadIdx.x & 63;
    int n0 = blockIdx.x * 8 + w * 2, n1 = n0 + 1;
    __shared__ float xs[8][256];
    if (n0 < n) {
        float4 u = ((const float4*)(x + (size_t)n0 * 256))[l];
        xs[w * 2][l * 4 + 0] = u.x; xs[w * 2][l * 4 + 1] = u.y;
        xs[w * 2][l * 4 + 2] = u.z; xs[w * 2][l * 4 + 3] = u.w;
    }
    if (n1 < n) {
        float4 u = ((const float4*)(x + (size_t)n1 * 256))[l];
        xs[w * 2 + 1][l * 4 + 0] = u.x; xs[w * 2 + 1][l * 4 + 1] = u.y;
        xs[w * 2 + 1][l * 4 + 2] = u.z; xs[w * 2 + 1][l * 4 + 3] = u.w;
    }
    __syncthreads();
    if (n0 >= n) return;
    float a0 = 0.f, a1 = 0.f;
    #pragma unroll 8
    for (int k = 0; k < 256; k++) {
        float wv = W1[k * 64 + l];
        a0 += xs[w * 2][k] * wv;
        a1 += xs[w * 2 + 1][k] * wv;
    }
    C[(size_t)n0 * 128 + l] = a0;
    if (n1 < n) C[(size_t)n1 * 128 + l] = a1;
}

// ------- GCN1 aggregate: h1 = relu(Anorm*xw1 + b1) -> B  (4x16-lane groups, float4) -------
__global__ __launch_bounds__(256) void k_agg1(const float* __restrict__ C,
                                              const int* __restrict__ csr,
                                              const int* __restrict__ rowptr,
                                              const float* __restrict__ wnorm,
                                              const float* __restrict__ dinv,
                                              const float* __restrict__ b1,
                                              float* __restrict__ B, int n) {
    int t = threadIdx.x;
    int w = t >> 6, l = t & 63, g = l >> 4, li = l & 15;
    int node = blockIdx.x * 4 + w;
    if (node >= n) return;
    int beg = rowptr[node], end = rowptr[node + 1];
    float ax = 0.f, ay = 0.f, az = 0.f, aw = 0.f;
    for (int e0 = beg; e0 < end; e0 += 4) {
        int e = e0 + g;
        bool valid = (e < end);
        int s = valid ? csr[e] : 0;
        float wn = valid ? wnorm[e] : 0.f;
        float4 c4 = *(const float4*)(C + (size_t)s * 128 + li * 4);
        ax += c4.x * wn; ay += c4.y * wn; az += c4.z * wn; aw += c4.w * wn;
    }
    float4 acc = make_float4(ax, ay, az, aw);
    float4 p = shfl_xor4(acc, 16);
    acc.x += p.x; acc.y += p.y; acc.z += p.z; acc.w += p.w;
    p = shfl_xor4(acc, 32);
    acc.x += p.x; acc.y += p.y; acc.z += p.z; acc.w += p.w;
    if (g == 0) {
        float di = dinv[node], di2 = di * di;
        float4 self = *(const float4*)(C + (size_t)node * 128 + li * 4);
        float4 bv = *(const float4*)(b1 + li * 4);
        float4 r;
        r.x = fmaxf(acc.x + self.x * di2 + bv.x, 0.f);
        r.y = fmaxf(acc.y + self.y * di2 + bv.y, 0.f);
        r.z = fmaxf(acc.z + self.z * di2 + bv.z, 0.f);
        r.w = fmaxf(acc.w + self.w * di2 + bv.w, 0.f);
        *(float4*)(B + (size_t)node * 64 + li * 4) = r;
    }
}

// ------- lin_qkvs: q (in-place over h1 in B), k||v -> C, skip -> h2 -------
__global__ __launch_bounds__(256) void k_lin_qkvs(float* __restrict__ B,
                                                  const float* __restrict__ Wq, const float* __restrict__ bq,
                                                  const float* __restrict__ Wk, const float* __restrict__ bk,
                                                  const float* __restrict__ Wv, const float* __restrict__ bv,
                                                  const float* __restrict__ Ws, const float* __restrict__ bs,
                                                  float* __restrict__ C, float* __restrict__ h2, int n) {
    int w = threadIdx.x >> 6, l = threadIdx.x & 63;
    int n0 = blockIdx.x * 8 + w * 2, n1 = n0 + 1;
    __shared__ float hs[8][64];
    if (n0 < n) hs[w * 2][l] = B[(size_t)n0 * 64 + l];
    if (n1 < n) hs[w * 2 + 1][l] = B[(size_t)n1 * 64 + l];
    __syncthreads();
    if (n0 >= n) return;
    float q0 = 0, k0 = 0, v0 = 0, s0 = 0, q1 = 0, k1 = 0, v1 = 0, s1 = 0;
    #pragma unroll 4
    for (int kk = 0; kk < 64; kk++) {
        float h0 = hs[w * 2][kk], h1v = hs[w * 2 + 1][kk];
        float wq = Wq[kk * 64 + l]; q0 += h0 * wq; q1 += h1v * wq;
        float wk = Wk[kk * 64 + l]; k0 += h0 * wk; k1 += h1v * wk;
        float wv = Wv[kk * 64 + l]; v0 += h0 * wv; v1 += h1v * wv;
        float ws_ = Ws[kk * 64 + l]; s0 += h0 * ws_; s1 += h1v * ws_;
    }
    float bql = bq[l], bkl = bk[l], bvl = bv[l], bsl = bs[l];
    C[(size_t)n0 * 128 + l]      = k0 + bkl;
    C[(size_t)n0 * 128 + 64 + l] = v0 + bvl;
    B[(size_t)n0 * 64 + l]       = q0 + bql;   // in-place: own row only
    h2[(size_t)n0 * 64 + l]      = s0 + bsl;   // skip pre-stored
    if (n1 < n) {
        C[(size_t)n1 * 128 + l]      = k1 + bkl;
        C[(size_t)n1 * 128 + 64 + l] = v1 + bvl;
        B[(size_t)n1 * 64 + l]       = q1 + bql;
        h2[(size_t)n1 * 64 + l]      = s1 + bsl;
    }
}

// ------- attention: warp/node, 4x16-lane groups, 4 edges in flight, no LDS -------
__global__ __launch_bounds__(256) void k_attn(const float* __restrict__ B,
                                              const float* __restrict__ C,
                                              const int* __restrict__ csr,
                                              const int* __restrict__ rowptr,
                                              float* __restrict__ h2, int n) {
    int t = threadIdx.x;
    int w = t >> 6, l = t & 63, g = l >> 4, li = l & 15;
    int node = blockIdx.x * 4 + w;
    if (node >= n) return;
    float4 qv = *(const float4*)(B + (size_t)node * 64 + li * 4);
    int beg = rowptr[node], end = rowptr[node + 1];
    float m = -1e30f, den = 0.f;
    float4 acc = make_float4(0.f, 0.f, 0.f, 0.f);
    for (int e0 = beg; e0 < end; e0 += 4) {
        int e = e0 + g;
        bool valid = (e < end);
        int s = valid ? csr[e] : 0;
        const float4* Kp = (const float4*)(C + (size_t)s * 128);
        float4 k4 = Kp[li];
        float4 v4 = Kp[16 + li];
        float d = qv.x * k4.x + qv.y * k4.y + qv.z * k4.z + qv.w * k4.w;
        d += __shfl_xor(d, 1);
        d += __shfl_xor(d, 2);
        d += __shfl_xor(d, 4);
        d += __shfl_xor(d, 8);
        float logit = valid ? d * 0.125f : -1e30f;
        float nm = fmaxf(m, logit);
        float r = __expf(m - nm);
        float pp = valid ? __expf(logit - nm) : 0.f;
        den = den * r + pp;
        acc.x = acc.x * r + pp * v4.x;
        acc.y = acc.y * r + pp * v4.y;
        acc.z = acc.z * r + pp * v4.z;
        acc.w = acc.w * r + pp * v4.w;
        m = nm;
    }
    // merge 4 group states (online-softmax merge), butterfly over xor 16, 32
    #pragma unroll
    for (int off = 16; off <= 32; off <<= 1) {
        float mo = __shfl_xor(m, off);
        float deno = __shfl_xor(den, off);
        float4 acco = shfl_xor4(acc, off);
        float nm = fmaxf(m, mo);
        float r = __expf(m - nm), ro = __expf(mo - nm);
        den = den * r + deno * ro;
        acc.x = acc.x * r + acco.x * ro;
        acc.y = acc.y * r + acco.y * ro;
        acc.z = acc.z * r + acco.z * ro;
        acc.w = acc.w * r + acco.w * ro;
        m = nm;
    }
    if (g == 0) {
        float inv = (den > 0.f) ? 1.f / den : 0.f;
        float* hp = h2 + (size_t)node * 64 + li * 4;
        float4 skv = *(const float4*)hp;   // skip pre-stored by lin_qkvs
        float4 o;
        o.x = acc.x * inv + skv.x;
        o.y = acc.y * inv + skv.y;
        o.z = acc.z * inv + skv.z;
        o.w = acc.w * inv + skv.w;
        *(float4*)hp = o;
    }
}

// ------- fused GCN2 aggregate + GEMM2: out = (Anorm*h2) @ W2 + b2 -------
__global__ __launch_bounds__(256) void k_agg2gemm2(const float* __restrict__ h2,
                                                   const int* __restrict__ csr,
                                                   const int* __restrict__ rowptr,
                                                   const float* __restrict__ wnorm,
                                                   const float* __restrict__ dinv,
                                                   const float* __restrict__ W2,
                                                   const float* __restrict__ b2,
                                                   float* __restrict__ out, int n) {
    __shared__ float ag[16][64];
    int t = threadIdx.x, w = t >> 6, l = t & 63, g = l >> 4, li = l & 15;
    int base = blockIdx.x * 16;
    for (int i = w; i < 16; i += 4) {
        int node = base + i;
        float ax = 0.f, ay = 0.f, az = 0.f, aw = 0.f;
        if (node < n) {
            int beg = rowptr[node], end = rowptr[node + 1];
            for (int e0 = beg; e0 < end; e0 += 4) {
                int e = e0 + g;
                bool valid = (e < end);
                int s = valid ? csr[e] : 0;
                float wn = valid ? wnorm[e] : 0.f;
                float4 h4 = *(const float4*)(h2 + (size_t)s * 64 + li * 4);
                ax += h4.x * wn; ay += h4.y * wn; az += h4.z * wn; aw += h4.w * wn;
            }
        }
        float4 acc = make_float4(ax, ay, az, aw);
        float4 p = shfl_xor4(acc, 16);
        acc.x += p.x; acc.y += p.y; acc.z += p.z; acc.w += p.w;
        p = shfl_xor4(acc, 32);
        acc.x += p.x; acc.y += p.y; acc.z += p.z; acc.w += p.w;
        if (g == 0) {
            if (node < n) {
                float di = dinv[node], di2 = di * di;
                float4 self = *(const float4*)(h2 + (size_t)node * 64 + li * 4);
                acc.x += self.x * di2; acc.y += self.y * di2;
                acc.z += self.z * di2; acc.w += self.w * di2;
            }
            *(float4*)&ag[i][li * 4] = acc;
        }
    }
    __syncthreads();
    float r[16];
    float bias = b2[t];
    #pragma unroll
    for (int i = 0; i < 16; i++) r[i] = bias;
    for (int k = 0; k < 64; k++) {
        float wv = W2[k * 256 + t];
        #pragma unroll
        for (int i = 0; i < 16; i++) r[i] += ag[i][k] * wv;
    }
    for (int i = 0; i < 16; i++) {
        int node = base + i;
        if (node < n) out[(size_t)node * 256 + t] = r[i];
    }
}

extern "C" void kernel_launch(void* const* d_in, const int* in_sizes, int n_in,
                              void* d_out, int out_size, void* d_ws, size_t ws_size,
                              hipStream_t stream) {
    const float* x  = (const float*)d_in[0];
    const int*   ei = (const int*)d_in[1];
    const float* W1 = (const float*)d_in[2];
    const float* b1 = (const float*)d_in[3];
    const float* Wq = (const float*)d_in[4];
    const float* bq = (const float*)d_in[5];
    const float* Wk = (const float*)d_in[6];
    const float* bk = (const float*)d_in[7];
    const float* Wv = (const float*)d_in[8];
    const float* bv = (const float*)d_in[9];
    const float* Ws = (const float*)d_in[10];
    const float* bs = (const float*)d_in[11];
    const float* W2 = (const float*)d_in[12];
    const float* b2 = (const float*)d_in[13];
    float* out = (float*)d_out;

    const int N = in_sizes[0] / 256;
    const int E = in_sizes[1] / 2;

    // d_out staging: C = [N][128] (xw1 slot0, then k||v), B = [N][64] (h1, then q in-place).
    // Both dead before k_agg2gemm2 rewrites out.
    float* C = (float*)d_out;
    float* B = (float*)d_out + (size_t)N * 128;

    // d_ws (~40 MB): CSR machinery + per-edge norm + h2
    char* p = (char*)d_ws;
    auto alloc = [&](size_t bytes) { char* r = p; p += (bytes + 255) & ~(size_t)255; return r; };
    int*   cnt    = (int*)alloc((size_t)N * 4);        // becomes scatter cursor
    int*   rowptr = (int*)alloc((size_t)(N + 1) * 4);
    int*   bsums  = (int*)alloc(1024);
    int*   csr    = (int*)alloc((size_t)E * 4);
    float* dinv   = (float*)alloc((size_t)N * 4);
    float* wnorm  = (float*)alloc((size_t)E * 4);
    float* h2     = (float*)alloc((size_t)N * 64 * 4);

    const int NB = (N + 1023) / 1024;

    hipMemsetAsync(cnt, 0, (size_t)N * 4, stream);
    k_hist<<<(E + 255) / 256, 256, 0, stream>>>(ei + E, cnt, E);
    k_blocksum<<<NB, 256, 0, stream>>>(cnt, bsums, N);
    k_scan_bsums<<<1, 64, 0, stream>>>(bsums, NB);
    k_scan_final<<<NB, 256, 0, stream>>>(cnt, bsums, rowptr, dinv, N, E);
    k_scatter<<<(E + 255) / 256, 256, 0, stream>>>(ei, cnt, dinv, csr, wnorm, E);

    k_gemm1<<<(N + 7) / 8, 256, 0, stream>>>(x, W1, C, N);
    k_agg1<<<(N + 3) / 4, 256, 0, stream>>>(C, csr, rowptr, wnorm, dinv, b1, B, N);
    k_lin_qkvs<<<(N + 7) / 8, 256, 0, stream>>>(B, Wq, bq, Wk, bk, Wv, bv, Ws, bs, C, h2, N);
    k_attn<<<(N + 3) / 4, 256, 0, stream>>>(B, C, csr, rowptr, h2, N);
    k_agg2gemm2<<<(N + 15) / 16, 256, 0, stream>>>(h2, csr, rowptr, wnorm, dinv, W2, b2, out, N);
}

// Round 8
// 658.170 us; speedup vs baseline: 1.9069x; 1.0915x over previous
//
#include <hip/hip_runtime.h>
#include <hip/hip_bf16.h>

typedef unsigned short u16;
typedef unsigned int u32;

__device__ __forceinline__ float bl(u32 u) { union { u32 i; float f; } c; c.i = u << 16; return c.f; }
__device__ __forceinline__ float bh(u32 u) { union { u32 i; float f; } c; c.i = u & 0xffff0000u; return c.f; }
__device__ __forceinline__ u16 f2us(float f) {
    __hip_bfloat16 h = __float2bfloat16(f);
    return *reinterpret_cast<u16*>(&h);
}
__device__ __forceinline__ u32 pk2(float a, float b) {
    return (u32)f2us(a) | ((u32)f2us(b) << 16);
}
__device__ __forceinline__ void up8(uint4 u, float* f) {
    f[0] = bl(u.x); f[1] = bh(u.x); f[2] = bl(u.y); f[3] = bh(u.y);
    f[4] = bl(u.z); f[5] = bh(u.z); f[6] = bl(u.w); f[7] = bh(u.w);
}

// ---------------- CSR build ----------------
__global__ void k_hist(const int* __restrict__ dst, int* __restrict__ cnt, int E) {
    int e = blockIdx.x * 256 + threadIdx.x;
    if (e < E) atomicAdd(&cnt[dst[e]], 1);
}

__global__ void k_blocksum(const int* __restrict__ cnt, int* __restrict__ bsums, int n) {
    int base = blockIdx.x * 1024;
    int t = threadIdx.x;
    int s = 0;
    for (int j = t; j < 1024; j += 256) { int i = base + j; if (i < n) s += cnt[i]; }
    __shared__ int red[256];
    red[t] = s; __syncthreads();
    for (int off = 128; off > 0; off >>= 1) { if (t < off) red[t] += red[t + off]; __syncthreads(); }
    if (t == 0) bsums[blockIdx.x] = red[0];
}

__global__ void k_scan_bsums(int* __restrict__ bsums, int nb) {
    if (threadIdx.x == 0) {
        int run = 0;
        for (int i = 0; i < nb; i++) { int v = bsums[i]; bsums[i] = run; run += v; }
    }
}

__global__ void k_scan_final(int* __restrict__ cnt, const int* __restrict__ bsums,
                             int* __restrict__ rowptr, float* __restrict__ dinv, int n, int E) {
    int base = blockIdx.x * 1024;
    int t = threadIdx.x;
    int i0 = base + t * 4;
    int v[4]; int s = 0;
    for (int j = 0; j < 4; j++) { int i = i0 + j; v[j] = (i < n) ? cnt[i] : 0; s += v[j]; }
    __shared__ int sc[256];
    sc[t] = s; __syncthreads();
    int acc = s;
    for (int off = 1; off < 256; off <<= 1) {
        int add = (t >= off) ? sc[t - off] : 0;
        __syncthreads();
        acc += add; sc[t] = acc;
        __syncthreads();
    }
    int run = acc - s + bsums[blockIdx.x];
    for (int j = 0; j < 4; j++) {
        int i = i0 + j;
        if (i < n) {
            rowptr[i] = run;
            dinv[i] = rsqrtf((float)(v[j] + 1));
            cnt[i] = run;   // cursor for scatter
            run += v[j];
        }
    }
    if (blockIdx.x == 0 && t == 0) rowptr[n] = E;
}

__global__ void k_scatter(const int* __restrict__ ei, int* __restrict__ cursor,
                          const float* __restrict__ dinv,
                          int* __restrict__ csr, float* __restrict__ wnorm, int E) {
    int e = blockIdx.x * 256 + threadIdx.x;
    if (e < E) {
        int s = ei[e], d = ei[E + e];
        int pos = atomicAdd(&cursor[d], 1);
        csr[pos] = s;
        wnorm[pos] = dinv[s] * dinv[d];
    }
}

// ---------------- GEMM1: xw1 = x @ W1 -> xw1b (bf16 [N][64]) ----------------
__global__ __launch_bounds__(256) void k_gemm1(const float* __restrict__ x,
                                               const float* __restrict__ W1,
                                               u16* __restrict__ xw1b, int n) {
    int w = threadIdx.x >> 6, l = threadIdx.x & 63;
    int n0 = blockIdx.x * 8 + w * 2, n1 = n0 + 1;
    __shared__ float xs[8][256];
    if (n0 < n) {
        float4 u = ((const float4*)(x + (size_t)n0 * 256))[l];
        xs[w * 2][l * 4 + 0] = u.x; xs[w * 2][l * 4 + 1] = u.y;
        xs[w * 2][l * 4 + 2] = u.z; xs[w * 2][l * 4 + 3] = u.w;
    }
    if (n1 < n) {
        float4 u = ((const float4*)(x + (size_t)n1 * 256))[l];
        xs[w * 2 + 1][l * 4 + 0] = u.x; xs[w * 2 + 1][l * 4 + 1] = u.y;
        xs[w * 2 + 1][l * 4 + 2] = u.z; xs[w * 2 + 1][l * 4 + 3] = u.w;
    }
    __syncthreads();
    if (n0 >= n) return;
    float a0 = 0.f, a1 = 0.f;
    #pragma unroll 8
    for (int k = 0; k < 256; k++) {
        float wv = W1[k * 64 + l];
        a0 += xs[w * 2][k] * wv;
        a1 += xs[w * 2 + 1][k] * wv;
    }
    xw1b[(size_t)n0 * 64 + l] = f2us(a0);
    if (n1 < n) xw1b[(size_t)n1 * 64 + l] = f2us(a1);
}

// ------- GCN1 aggregate: h1 = relu(Anorm*xw1 + b1) -> B (f32). 8x8-lane groups. -------
__global__ __launch_bounds__(256) void k_agg1(const u16* __restrict__ xw1b,
                                              const int* __restrict__ csr,
                                              const int* __restrict__ rowptr,
                                              const float* __restrict__ wnorm,
                                              const float* __restrict__ dinv,
                                              const float* __restrict__ b1,
                                              float* __restrict__ B, int n) {
    int t = threadIdx.x;
    int w = t >> 6, l = t & 63, g = l >> 3, li = l & 7;
    int node = blockIdx.x * 4 + w;
    if (node >= n) return;
    int beg = rowptr[node], end = rowptr[node + 1];
    float a[8];
    #pragma unroll
    for (int j = 0; j < 8; j++) a[j] = 0.f;
    for (int e0 = beg; e0 < end; e0 += 8) {
        int e = e0 + g;
        bool valid = (e < end);
        int s = valid ? csr[e] : 0;
        float wn = valid ? wnorm[e] : 0.f;
        uint4 u = *(const uint4*)(xw1b + (size_t)s * 64 + li * 8);
        float f[8]; up8(u, f);
        #pragma unroll
        for (int j = 0; j < 8; j++) a[j] += f[j] * wn;
    }
    #pragma unroll
    for (int off = 8; off <= 32; off <<= 1)
        #pragma unroll
        for (int j = 0; j < 8; j++) a[j] += __shfl_xor(a[j], off);
    if (g == 0) {
        float di = dinv[node], di2 = di * di;
        uint4 u = *(const uint4*)(xw1b + (size_t)node * 64 + li * 8);
        float sf[8]; up8(u, sf);
        float4 bv0 = *(const float4*)(b1 + li * 8);
        float4 bv1 = *(const float4*)(b1 + li * 8 + 4);
        float bb[8] = {bv0.x, bv0.y, bv0.z, bv0.w, bv1.x, bv1.y, bv1.z, bv1.w};
        float r[8];
        #pragma unroll
        for (int j = 0; j < 8; j++) r[j] = fmaxf(a[j] + sf[j] * di2 + bb[j], 0.f);
        float* dst = B + (size_t)node * 64 + li * 8;
        *(float4*)dst = make_float4(r[0], r[1], r[2], r[3]);
        *(float4*)(dst + 4) = make_float4(r[4], r[5], r[6], r[7]);
    }
}

// ------- lin_qkvs: q (f32, in-place over h1 in B), K||V -> kvb (bf16), skip -> h2b (bf16) -------
__global__ __launch_bounds__(256) void k_lin_qkvs(float* __restrict__ B,
                                                  const float* __restrict__ Wq, const float* __restrict__ bq,
                                                  const float* __restrict__ Wk, const float* __restrict__ bk,
                                                  const float* __restrict__ Wv, const float* __restrict__ bv,
                                                  const float* __restrict__ Ws, const float* __restrict__ bs,
                                                  u16* __restrict__ kvb, u16* __restrict__ h2b, int n) {
    int w = threadIdx.x >> 6, l = threadIdx.x & 63;
    int n0 = blockIdx.x * 8 + w * 2, n1 = n0 + 1;
    __shared__ float hs[8][64];
    if (n0 < n) hs[w * 2][l] = B[(size_t)n0 * 64 + l];
    if (n1 < n) hs[w * 2 + 1][l] = B[(size_t)n1 * 64 + l];
    __syncthreads();
    if (n0 >= n) return;
    float q0 = 0, k0 = 0, v0 = 0, s0 = 0, q1 = 0, k1 = 0, v1 = 0, s1 = 0;
    #pragma unroll 4
    for (int kk = 0; kk < 64; kk++) {
        float h0 = hs[w * 2][kk], h1v = hs[w * 2 + 1][kk];
        float wq = Wq[kk * 64 + l]; q0 += h0 * wq; q1 += h1v * wq;
        float wk = Wk[kk * 64 + l]; k0 += h0 * wk; k1 += h1v * wk;
        float wv = Wv[kk * 64 + l]; v0 += h0 * wv; v1 += h1v * wv;
        float ws_ = Ws[kk * 64 + l]; s0 += h0 * ws_; s1 += h1v * ws_;
    }
    float bql = bq[l], bkl = bk[l], bvl = bv[l], bsl = bs[l];
    kvb[(size_t)n0 * 128 + l]      = f2us(k0 + bkl);
    kvb[(size_t)n0 * 128 + 64 + l] = f2us(v0 + bvl);
    B[(size_t)n0 * 64 + l]         = q0 + bql;       // in-place: own row only
    h2b[(size_t)n0 * 64 + l]       = f2us(s0 + bsl); // skip pre-stored
    if (n1 < n) {
        kvb[(size_t)n1 * 128 + l]      = f2us(k1 + bkl);
        kvb[(size_t)n1 * 128 + 64 + l] = f2us(v1 + bvl);
        B[(size_t)n1 * 64 + l]         = q1 + bql;
        h2b[(size_t)n1 * 64 + l]       = f2us(s1 + bsl);
    }
}

// ------- attention: warp/node, 8x8-lane groups, bf16 K/V gather, no LDS -------
__global__ __launch_bounds__(256) void k_attn(const float* __restrict__ B,
                                              const u16* __restrict__ kvb,
                                              const int* __restrict__ csr,
                                              const int* __restrict__ rowptr,
                                              u16* __restrict__ h2b, int n) {
    int t = threadIdx.x;
    int w = t >> 6, l = t & 63, g = l >> 3, li = l & 7;
    int node = blockIdx.x * 4 + w;
    if (node >= n) return;
    const float* qp = B + (size_t)node * 64 + li * 8;
    float4 qa = *(const float4*)qp;
    float4 qb = *(const float4*)(qp + 4);
    float q[8] = {qa.x, qa.y, qa.z, qa.w, qb.x, qb.y, qb.z, qb.w};
    int beg = rowptr[node], end = rowptr[node + 1];
    float m = -1e30f, den = 0.f;
    float acc[8];
    #pragma unroll
    for (int j = 0; j < 8; j++) acc[j] = 0.f;
    for (int e0 = beg; e0 < end; e0 += 8) {
        int e = e0 + g;
        bool valid = (e < end);
        int s = valid ? csr[e] : 0;
        const u16* row = kvb + (size_t)s * 128;
        uint4 ku = *(const uint4*)(row + li * 8);
        uint4 vu = *(const uint4*)(row + 64 + li * 8);
        float kf[8]; up8(ku, kf);
        float vf[8]; up8(vu, vf);
        float d = 0.f;
        #pragma unroll
        for (int j = 0; j < 8; j++) d += q[j] * kf[j];
        d += __shfl_xor(d, 1);
        d += __shfl_xor(d, 2);
        d += __shfl_xor(d, 4);
        float logit = valid ? d * 0.125f : -1e30f;
        float nm = fmaxf(m, logit);
        float r = __expf(m - nm);
        float pp = valid ? __expf(logit - nm) : 0.f;
        den = den * r + pp;
        #pragma unroll
        for (int j = 0; j < 8; j++) acc[j] = acc[j] * r + pp * vf[j];
        m = nm;
    }
    // merge 8 group states: butterfly xor 8,16,32 (online-softmax merge)
    #pragma unroll
    for (int off = 8; off <= 32; off <<= 1) {
        float mo = __shfl_xor(m, off);
        float deno = __shfl_xor(den, off);
        float nm = fmaxf(m, mo);
        float r = __expf(m - nm), ro = __expf(mo - nm);
        den = den * r + deno * ro;
        #pragma unroll
        for (int j = 0; j < 8; j++) {
            float ao = __shfl_xor(acc[j], off);
            acc[j] = acc[j] * r + ao * ro;
        }
        m = nm;
    }
    if (g == 0) {
        float inv = (den > 0.f) ? 1.f / den : 0.f;
        u16* hp = h2b + (size_t)node * 64 + li * 8;
        uint4 su = *(const uint4*)hp;    // skip pre-stored by lin_qkvs
        float sk[8]; up8(su, sk);
        float o[8];
        #pragma unroll
        for (int j = 0; j < 8; j++) o[j] = acc[j] * inv + sk[j];
        uint4 ou;
        ou.x = pk2(o[0], o[1]); ou.y = pk2(o[2], o[3]);
        ou.z = pk2(o[4], o[5]); ou.w = pk2(o[6], o[7]);
        *(uint4*)hp = ou;
    }
}

// ------- fused GCN2 aggregate + GEMM2: out = (Anorm*h2) @ W2 + b2. 8-lane groups + float4 LDS. -------
__global__ __launch_bounds__(256) void k_agg2gemm2(const u16* __restrict__ h2b,
                                                   const int* __restrict__ csr,
                                                   const int* __restrict__ rowptr,
                                                   const float* __restrict__ wnorm,
                                                   const float* __restrict__ dinv,
                                                   const float* __restrict__ W2,
                                                   const float* __restrict__ b2,
                                                   float* __restrict__ out, int n) {
    __shared__ float ag[16][64];
    int t = threadIdx.x, w = t >> 6, l = t & 63, g = l >> 3, li = l & 7;
    int base = blockIdx.x * 16;
    for (int i = w; i < 16; i += 4) {
        int node = base + i;
        float a[8];
        #pragma unroll
        for (int j = 0; j < 8; j++) a[j] = 0.f;
        if (node < n) {
            int beg = rowptr[node], end = rowptr[node + 1];
            for (int e0 = beg; e0 < end; e0 += 8) {
                int e = e0 + g;
                bool valid = (e < end);
                int s = valid ? csr[e] : 0;
                float wn = valid ? wnorm[e] : 0.f;
                uint4 u = *(const uint4*)(h2b + (size_t)s * 64 + li * 8);
                float f[8]; up8(u, f);
                #pragma unroll
                for (int j = 0; j < 8; j++) a[j] += f[j] * wn;
            }
        }
        #pragma unroll
        for (int off = 8; off <= 32; off <<= 1)
            #pragma unroll
            for (int j = 0; j < 8; j++) a[j] += __shfl_xor(a[j], off);
        if (g == 0) {
            if (node < n) {
                float di = dinv[node], di2 = di * di;
                uint4 u = *(const uint4*)(h2b + (size_t)node * 64 + li * 8);
                float sf[8]; up8(u, sf);
                #pragma unroll
                for (int j = 0; j < 8; j++) a[j] += sf[j] * di2;
            }
            float* dst = &ag[i][li * 8];
            *(float4*)dst = make_float4(a[0], a[1], a[2], a[3]);
            *(float4*)(dst + 4) = make_float4(a[4], a[5], a[6], a[7]);
        }
    }
    __syncthreads();
    float r[16];
    float bias = b2[t];
    #pragma unroll
    for (int i = 0; i < 16; i++) r[i] = bias;
    for (int k4 = 0; k4 < 16; k4++) {
        float w0 = W2[(k4 * 4 + 0) * 256 + t];
        float w1 = W2[(k4 * 4 + 1) * 256 + t];
        float w2 = W2[(k4 * 4 + 2) * 256 + t];
        float w3 = W2[(k4 * 4 + 3) * 256 + t];
        #pragma unroll
        for (int i = 0; i < 16; i++) {
            float4 av = *(const float4*)&ag[i][k4 * 4];
            r[i] += av.x * w0 + av.y * w1 + av.z * w2 + av.w * w3;
        }
    }
    for (int i = 0; i < 16; i++) {
        int node = base + i;
        if (node < n) out[(size_t)node * 256 + t] = r[i];
    }
}

extern "C" void kernel_launch(void* const* d_in, const int* in_sizes, int n_in,
                              void* d_out, int out_size, void* d_ws, size_t ws_size,
                              hipStream_t stream) {
    const float* x  = (const float*)d_in[0];
    const int*   ei = (const int*)d_in[1];
    const float* W1 = (const float*)d_in[2];
    const float* b1 = (const float*)d_in[3];
    const float* Wq = (const float*)d_in[4];
    const float* bq = (const float*)d_in[5];
    const float* Wk = (const float*)d_in[6];
    const float* bk = (const float*)d_in[7];
    const float* Wv = (const float*)d_in[8];
    const float* bv = (const float*)d_in[9];
    const float* Ws = (const float*)d_in[10];
    const float* bs = (const float*)d_in[11];
    const float* W2 = (const float*)d_in[12];
    const float* b2 = (const float*)d_in[13];
    float* out = (float*)d_out;

    const int N = in_sizes[0] / 256;
    const int E = in_sizes[1] / 2;

    // d_out staging (all dead before k_agg2gemm2 rewrites out):
    //   kvb  bf16 [N][128] (K||V)      25.6 MB
    //   xw1b bf16 [N][64]              12.8 MB
    //   B    f32  [N][64] (h1 then q)  25.6 MB   -> 64 MB <= out 100 MB
    char* ob = (char*)d_out;
    u16*   kvb  = (u16*)ob;
    u16*   xw1b = (u16*)(ob + (size_t)N * 128 * 2);
    float* B    = (float*)(ob + (size_t)N * 128 * 2 + (size_t)N * 64 * 2);

    // d_ws (~27 MB): CSR machinery + per-edge norm + h2 (bf16)
    char* p = (char*)d_ws;
    auto alloc = [&](size_t bytes) { char* r = p; p += (bytes + 255) & ~(size_t)255; return r; };
    int*   cnt    = (int*)alloc((size_t)N * 4);        // becomes scatter cursor
    int*   rowptr = (int*)alloc((size_t)(N + 1) * 4);
    int*   bsums  = (int*)alloc(1024);
    int*   csr    = (int*)alloc((size_t)E * 4);
    float* dinv   = (float*)alloc((size_t)N * 4);
    float* wnorm  = (float*)alloc((size_t)E * 4);
    u16*   h2b    = (u16*)alloc((size_t)N * 64 * 2);

    const int NB = (N + 1023) / 1024;

    hipMemsetAsync(cnt, 0, (size_t)N * 4, stream);
    k_hist<<<(E + 255) / 256, 256, 0, stream>>>(ei + E, cnt, E);
    k_blocksum<<<NB, 256, 0, stream>>>(cnt, bsums, N);
    k_scan_bsums<<<1, 64, 0, stream>>>(bsums, NB);
    k_scan_final<<<NB, 256, 0, stream>>>(cnt, bsums, rowptr, dinv, N, E);
    k_scatter<<<(E + 255) / 256, 256, 0, stream>>>(ei, cnt, dinv, csr, wnorm, E);

    k_gemm1<<<(N + 7) / 8, 256, 0, stream>>>(x, W1, xw1b, N);
    k_agg1<<<(N + 3) / 4, 256, 0, stream>>>(xw1b, csr, rowptr, wnorm, dinv, b1, B, N);
    k_lin_qkvs<<<(N + 7) / 8, 256, 0, stream>>>(B, Wq, bq, Wk, bk, Wv, bv, Ws, bs, kvb, h2b, N);
    k_attn<<<(N + 3) / 4, 256, 0, stream>>>(B, kvb, csr, rowptr, h2b, N);
    k_agg2gemm2<<<(N + 15) / 16, 256, 0, stream>>>(h2b, csr, rowptr, wnorm, dinv, W2, b2, out, N);
}

// Round 9
// 642.615 us; speedup vs baseline: 1.9530x; 1.0242x over previous
//
#include <hip/hip_runtime.h>
#include <hip/hip_bf16.h>

typedef unsigned short u16;
typedef unsigned int u32;

__device__ __forceinline__ float bl(u32 u) { union { u32 i; float f; } c; c.i = u << 16; return c.f; }
__device__ __forceinline__ float bh(u32 u) { union { u32 i; float f; } c; c.i = u & 0xffff0000u; return c.f; }
__device__ __forceinline__ u16 f2us(float f) {
    __hip_bfloat16 h = __float2bfloat16(f);
    return *reinterpret_cast<u16*>(&h);
}
__device__ __forceinline__ u32 pk2(float a, float b) {
    return (u32)f2us(a) | ((u32)f2us(b) << 16);
}
__device__ __forceinline__ void up8(uint4 u, float* f) {
    f[0] = bl(u.x); f[1] = bh(u.x); f[2] = bl(u.y); f[3] = bh(u.y);
    f[4] = bl(u.z); f[5] = bh(u.z); f[6] = bl(u.w); f[7] = bh(u.w);
}

// ---------------- CSR build ----------------
__global__ void k_hist(const int* __restrict__ dst, int* __restrict__ cnt, int E) {
    int e = blockIdx.x * 256 + threadIdx.x;
    if (e < E) atomicAdd(&cnt[dst[e]], 1);
}

__global__ void k_blocksum(const int* __restrict__ cnt, int* __restrict__ bsums, int n) {
    int base = blockIdx.x * 1024;
    int t = threadIdx.x;
    int s = 0;
    for (int j = t; j < 1024; j += 256) { int i = base + j; if (i < n) s += cnt[i]; }
    __shared__ int red[256];
    red[t] = s; __syncthreads();
    for (int off = 128; off > 0; off >>= 1) { if (t < off) red[t] += red[t + off]; __syncthreads(); }
    if (t == 0) bsums[blockIdx.x] = red[0];
}

__global__ void k_scan_bsums(int* __restrict__ bsums, int nb) {
    if (threadIdx.x == 0) {
        int run = 0;
        for (int i = 0; i < nb; i++) { int v = bsums[i]; bsums[i] = run; run += v; }
    }
}

__global__ void k_scan_final(int* __restrict__ cnt, const int* __restrict__ bsums,
                             int* __restrict__ rowptr, float* __restrict__ dinv, int n, int E) {
    int base = blockIdx.x * 1024;
    int t = threadIdx.x;
    int i0 = base + t * 4;
    int v[4]; int s = 0;
    for (int j = 0; j < 4; j++) { int i = i0 + j; v[j] = (i < n) ? cnt[i] : 0; s += v[j]; }
    __shared__ int sc[256];
    sc[t] = s; __syncthreads();
    int acc = s;
    for (int off = 1; off < 256; off <<= 1) {
        int add = (t >= off) ? sc[t - off] : 0;
        __syncthreads();
        acc += add; sc[t] = acc;
        __syncthreads();
    }
    int run = acc - s + bsums[blockIdx.x];
    for (int j = 0; j < 4; j++) {
        int i = i0 + j;
        if (i < n) {
            rowptr[i] = run;
            dinv[i] = rsqrtf((float)(v[j] + 1));
            cnt[i] = run;   // cursor for scatter
            run += v[j];
        }
    }
    if (blockIdx.x == 0 && t == 0) rowptr[n] = E;
}

// csr (4B, for attn) + edat int2 {src, wnorm} (8B, for GCN aggs)
__global__ void k_scatter(const int* __restrict__ ei, int* __restrict__ cursor,
                          const float* __restrict__ dinv,
                          int* __restrict__ csr, int2* __restrict__ edat, int E) {
    int e = blockIdx.x * 256 + threadIdx.x;
    if (e < E) {
        int s = ei[e], d = ei[E + e];
        int pos = atomicAdd(&cursor[d], 1);
        csr[pos] = s;
        edat[pos] = make_int2(s, __float_as_int(dinv[s] * dinv[d]));
    }
}

// ---------------- GEMM1: xw1 = x @ W1 -> xw1b (bf16 [N][64]) ----------------
__global__ __launch_bounds__(256) void k_gemm1(const float* __restrict__ x,
                                               const float* __restrict__ W1,
                                               u16* __restrict__ xw1b, int n) {
    int w = threadIdx.x >> 6, l = threadIdx.x & 63;
    int n0 = blockIdx.x * 8 + w * 2, n1 = n0 + 1;
    __shared__ float xs[8][256];
    if (n0 < n) {
        float4 u = ((const float4*)(x + (size_t)n0 * 256))[l];
        xs[w * 2][l * 4 + 0] = u.x; xs[w * 2][l * 4 + 1] = u.y;
        xs[w * 2][l * 4 + 2] = u.z; xs[w * 2][l * 4 + 3] = u.w;
    }
    if (n1 < n) {
        float4 u = ((const float4*)(x + (size_t)n1 * 256))[l];
        xs[w * 2 + 1][l * 4 + 0] = u.x; xs[w * 2 + 1][l * 4 + 1] = u.y;
        xs[w * 2 + 1][l * 4 + 2] = u.z; xs[w * 2 + 1][l * 4 + 3] = u.w;
    }
    __syncthreads();
    if (n0 >= n) return;
    float a0 = 0.f, a1 = 0.f;
    #pragma unroll 8
    for (int k = 0; k < 256; k++) {
        float wv = W1[k * 64 + l];
        a0 += xs[w * 2][k] * wv;
        a1 += xs[w * 2 + 1][k] * wv;
    }
    xw1b[(size_t)n0 * 64 + l] = f2us(a0);
    if (n1 < n) xw1b[(size_t)n1 * 64 + l] = f2us(a1);
}

// ------- GCN1 aggregate: h1 = relu(Anorm*xw1 + b1) -> B (f32). 8x8 groups, 16 edges in flight. -------
__global__ __launch_bounds__(256) void k_agg1(const u16* __restrict__ xw1b,
                                              const int2* __restrict__ edat,
                                              const int* __restrict__ rowptr,
                                              const float* __restrict__ dinv,
                                              const float* __restrict__ b1,
                                              float* __restrict__ B, int n) {
    int t = threadIdx.x;
    int w = t >> 6, l = t & 63, g = l >> 3, li = l & 7;
    int node = blockIdx.x * 4 + w;
    if (node >= n) return;
    int beg = rowptr[node], end = rowptr[node + 1];
    float a0[8], a1[8];
    #pragma unroll
    for (int j = 0; j < 8; j++) { a0[j] = 0.f; a1[j] = 0.f; }
    for (int e0 = beg; e0 < end; e0 += 16) {
        int eA = e0 + g, eB = e0 + 8 + g;
        bool vA = (eA < end), vB = (eB < end);
        int2 dA = vA ? edat[eA] : make_int2(0, 0);
        int2 dB = vB ? edat[eB] : make_int2(0, 0);
        uint4 uA = *(const uint4*)(xw1b + (size_t)dA.x * 64 + li * 8);
        uint4 uB = *(const uint4*)(xw1b + (size_t)dB.x * 64 + li * 8);
        float wA = __int_as_float(dA.y), wB = __int_as_float(dB.y);
        float fA[8]; up8(uA, fA);
        float fB[8]; up8(uB, fB);
        #pragma unroll
        for (int j = 0; j < 8; j++) { a0[j] += fA[j] * wA; a1[j] += fB[j] * wB; }
    }
    #pragma unroll
    for (int j = 0; j < 8; j++) a0[j] += a1[j];
    #pragma unroll
    for (int off = 8; off <= 32; off <<= 1)
        #pragma unroll
        for (int j = 0; j < 8; j++) a0[j] += __shfl_xor(a0[j], off);
    if (g == 0) {
        float di = dinv[node], di2 = di * di;
        uint4 u = *(const uint4*)(xw1b + (size_t)node * 64 + li * 8);
        float sf[8]; up8(u, sf);
        float4 bv0 = *(const float4*)(b1 + li * 8);
        float4 bv1 = *(const float4*)(b1 + li * 8 + 4);
        float bb[8] = {bv0.x, bv0.y, bv0.z, bv0.w, bv1.x, bv1.y, bv1.z, bv1.w};
        float r[8];
        #pragma unroll
        for (int j = 0; j < 8; j++) r[j] = fmaxf(a0[j] + sf[j] * di2 + bb[j], 0.f);
        float* dst = B + (size_t)node * 64 + li * 8;
        *(float4*)dst = make_float4(r[0], r[1], r[2], r[3]);
        *(float4*)(dst + 4) = make_float4(r[4], r[5], r[6], r[7]);
    }
}

// ------- lin_qkvs: q (f32, in-place over h1 in B), K||V -> kvb (bf16), skip -> h2b (bf16) -------
__global__ __launch_bounds__(256) void k_lin_qkvs(float* __restrict__ B,
                                                  const float* __restrict__ Wq, const float* __restrict__ bq,
                                                  const float* __restrict__ Wk, const float* __restrict__ bk,
                                                  const float* __restrict__ Wv, const float* __restrict__ bv,
                                                  const float* __restrict__ Ws, const float* __restrict__ bs,
                                                  u16* __restrict__ kvb, u16* __restrict__ h2b, int n) {
    int w = threadIdx.x >> 6, l = threadIdx.x & 63;
    int n0 = blockIdx.x * 8 + w * 2, n1 = n0 + 1;
    __shared__ float hs[8][64];
    if (n0 < n) hs[w * 2][l] = B[(size_t)n0 * 64 + l];
    if (n1 < n) hs[w * 2 + 1][l] = B[(size_t)n1 * 64 + l];
    __syncthreads();
    if (n0 >= n) return;
    float q0 = 0, k0 = 0, v0 = 0, s0 = 0, q1 = 0, k1 = 0, v1 = 0, s1 = 0;
    #pragma unroll 4
    for (int kk = 0; kk < 64; kk++) {
        float h0 = hs[w * 2][kk], h1v = hs[w * 2 + 1][kk];
        float wq = Wq[kk * 64 + l]; q0 += h0 * wq; q1 += h1v * wq;
        float wk = Wk[kk * 64 + l]; k0 += h0 * wk; k1 += h1v * wk;
        float wv = Wv[kk * 64 + l]; v0 += h0 * wv; v1 += h1v * wv;
        float ws_ = Ws[kk * 64 + l]; s0 += h0 * ws_; s1 += h1v * ws_;
    }
    float bql = bq[l], bkl = bk[l], bvl = bv[l], bsl = bs[l];
    kvb[(size_t)n0 * 128 + l]      = f2us(k0 + bkl);
    kvb[(size_t)n0 * 128 + 64 + l] = f2us(v0 + bvl);
    B[(size_t)n0 * 64 + l]         = q0 + bql;       // in-place: own row only
    h2b[(size_t)n0 * 64 + l]       = f2us(s0 + bsl); // skip pre-stored
    if (n1 < n) {
        kvb[(size_t)n1 * 128 + l]      = f2us(k1 + bkl);
        kvb[(size_t)n1 * 128 + 64 + l] = f2us(v1 + bvl);
        B[(size_t)n1 * 64 + l]         = q1 + bql;
        h2b[(size_t)n1 * 64 + l]       = f2us(s1 + bsl);
    }
}

// ------- attention: warp/node, 8x8 groups, 16 edges in flight (dual softmax state) -------
__global__ __launch_bounds__(256) void k_attn(const float* __restrict__ B,
                                              const u16* __restrict__ kvb,
                                              const int* __restrict__ csr,
                                              const int* __restrict__ rowptr,
                                              u16* __restrict__ h2b, int n) {
    int t = threadIdx.x;
    int w = t >> 6, l = t & 63, g = l >> 3, li = l & 7;
    int node = blockIdx.x * 4 + w;
    if (node >= n) return;
    const float* qp = B + (size_t)node * 64 + li * 8;
    float4 qa = *(const float4*)qp;
    float4 qb = *(const float4*)(qp + 4);
    float q[8] = {qa.x, qa.y, qa.z, qa.w, qb.x, qb.y, qb.z, qb.w};
    int beg = rowptr[node], end = rowptr[node + 1];
    float mA = -1e30f, denA = 0.f, mB = -1e30f, denB = 0.f;
    float accA[8], accB[8];
    #pragma unroll
    for (int j = 0; j < 8; j++) { accA[j] = 0.f; accB[j] = 0.f; }
    for (int e0 = beg; e0 < end; e0 += 16) {
        int eA = e0 + g, eB = e0 + 8 + g;
        bool vA = (eA < end), vB = (eB < end);
        int sA = vA ? csr[eA] : 0;
        int sB = vB ? csr[eB] : 0;
        const u16* rowA = kvb + (size_t)sA * 128;
        const u16* rowB = kvb + (size_t)sB * 128;
        uint4 kuA = *(const uint4*)(rowA + li * 8);
        uint4 vuA = *(const uint4*)(rowA + 64 + li * 8);
        uint4 kuB = *(const uint4*)(rowB + li * 8);
        uint4 vuB = *(const uint4*)(rowB + 64 + li * 8);
        float kf[8], vf[8];
        // state A
        up8(kuA, kf); up8(vuA, vf);
        float dA = 0.f;
        #pragma unroll
        for (int j = 0; j < 8; j++) dA += q[j] * kf[j];
        dA += __shfl_xor(dA, 1);
        dA += __shfl_xor(dA, 2);
        dA += __shfl_xor(dA, 4);
        float logitA = vA ? dA * 0.125f : -1e30f;
        float nmA = fmaxf(mA, logitA);
        float rA = __expf(mA - nmA);
        float pA = vA ? __expf(logitA - nmA) : 0.f;
        denA = denA * rA + pA;
        #pragma unroll
        for (int j = 0; j < 8; j++) accA[j] = accA[j] * rA + pA * vf[j];
        mA = nmA;
        // state B
        up8(kuB, kf); up8(vuB, vf);
        float dB = 0.f;
        #pragma unroll
        for (int j = 0; j < 8; j++) dB += q[j] * kf[j];
        dB += __shfl_xor(dB, 1);
        dB += __shfl_xor(dB, 2);
        dB += __shfl_xor(dB, 4);
        float logitB = vB ? dB * 0.125f : -1e30f;
        float nmB = fmaxf(mB, logitB);
        float rB = __expf(mB - nmB);
        float pB = vB ? __expf(logitB - nmB) : 0.f;
        denB = denB * rB + pB;
        #pragma unroll
        for (int j = 0; j < 8; j++) accB[j] = accB[j] * rB + pB * vf[j];
        mB = nmB;
    }
    // merge A,B
    float m = fmaxf(mA, mB);
    float rA = __expf(mA - m), rB = __expf(mB - m);
    float den = denA * rA + denB * rB;
    float acc[8];
    #pragma unroll
    for (int j = 0; j < 8; j++) acc[j] = accA[j] * rA + accB[j] * rB;
    // merge 8 group states: butterfly xor 8,16,32
    #pragma unroll
    for (int off = 8; off <= 32; off <<= 1) {
        float mo = __shfl_xor(m, off);
        float deno = __shfl_xor(den, off);
        float nm = fmaxf(m, mo);
        float r = __expf(m - nm), ro = __expf(mo - nm);
        den = den * r + deno * ro;
        #pragma unroll
        for (int j = 0; j < 8; j++) {
            float ao = __shfl_xor(acc[j], off);
            acc[j] = acc[j] * r + ao * ro;
        }
        m = nm;
    }
    if (g == 0) {
        float inv = (den > 0.f) ? 1.f / den : 0.f;
        u16* hp = h2b + (size_t)node * 64 + li * 8;
        uint4 su = *(const uint4*)hp;    // skip pre-stored by lin_qkvs
        float sk[8]; up8(su, sk);
        float o[8];
        #pragma unroll
        for (int j = 0; j < 8; j++) o[j] = acc[j] * inv + sk[j];
        uint4 ou;
        ou.x = pk2(o[0], o[1]); ou.y = pk2(o[2], o[3]);
        ou.z = pk2(o[4], o[5]); ou.w = pk2(o[6], o[7]);
        *(uint4*)hp = ou;
    }
}

// ------- fused GCN2 aggregate + GEMM2: out = (Anorm*h2) @ W2 + b2. 16 edges in flight. -------
__global__ __launch_bounds__(256) void k_agg2gemm2(const u16* __restrict__ h2b,
                                                   const int2* __restrict__ edat,
                                                   const int* __restrict__ rowptr,
                                                   const float* __restrict__ dinv,
                                                   const float* __restrict__ W2,
                                                   const float* __restrict__ b2,
                                                   float* __restrict__ out, int n) {
    __shared__ float ag[16][64];
    int t = threadIdx.x, w = t >> 6, l = t & 63, g = l >> 3, li = l & 7;
    int base = blockIdx.x * 16;
    for (int i = w; i < 16; i += 4) {
        int node = base + i;
        float a0[8], a1[8];
        #pragma unroll
        for (int j = 0; j < 8; j++) { a0[j] = 0.f; a1[j] = 0.f; }
        if (node < n) {
            int beg = rowptr[node], end = rowptr[node + 1];
            for (int e0 = beg; e0 < end; e0 += 16) {
                int eA = e0 + g, eB = e0 + 8 + g;
                bool vA = (eA < end), vB = (eB < end);
                int2 dA = vA ? edat[eA] : make_int2(0, 0);
                int2 dB = vB ? edat[eB] : make_int2(0, 0);
                uint4 uA = *(const uint4*)(h2b + (size_t)dA.x * 64 + li * 8);
                uint4 uB = *(const uint4*)(h2b + (size_t)dB.x * 64 + li * 8);
                float wA = __int_as_float(dA.y), wB = __int_as_float(dB.y);
                float fA[8]; up8(uA, fA);
                float fB[8]; up8(uB, fB);
                #pragma unroll
                for (int j = 0; j < 8; j++) { a0[j] += fA[j] * wA; a1[j] += fB[j] * wB; }
            }
        }
        #pragma unroll
        for (int j = 0; j < 8; j++) a0[j] += a1[j];
        #pragma unroll
        for (int off = 8; off <= 32; off <<= 1)
            #pragma unroll
            for (int j = 0; j < 8; j++) a0[j] += __shfl_xor(a0[j], off);
        if (g == 0) {
            if (node < n) {
                float di = dinv[node], di2 = di * di;
                uint4 u = *(const uint4*)(h2b + (size_t)node * 64 + li * 8);
                float sf[8]; up8(u, sf);
                #pragma unroll
                for (int j = 0; j < 8; j++) a0[j] += sf[j] * di2;
            }
            float* dst = &ag[i][li * 8];
            *(float4*)dst = make_float4(a0[0], a0[1], a0[2], a0[3]);
            *(float4*)(dst + 4) = make_float4(a0[4], a0[5], a0[6], a0[7]);
        }
    }
    __syncthreads();
    float r[16];
    float bias = b2[t];
    #pragma unroll
    for (int i = 0; i < 16; i++) r[i] = bias;
    for (int k4 = 0; k4 < 16; k4++) {
        float w0 = W2[(k4 * 4 + 0) * 256 + t];
        float w1 = W2[(k4 * 4 + 1) * 256 + t];
        float w2 = W2[(k4 * 4 + 2) * 256 + t];
        float w3 = W2[(k4 * 4 + 3) * 256 + t];
        #pragma unroll
        for (int i = 0; i < 16; i++) {
            float4 av = *(const float4*)&ag[i][k4 * 4];
            r[i] += av.x * w0 + av.y * w1 + av.z * w2 + av.w * w3;
        }
    }
    for (int i = 0; i < 16; i++) {
        int node = base + i;
        if (node < n) out[(size_t)node * 256 + t] = r[i];
    }
}

extern "C" void kernel_launch(void* const* d_in, const int* in_sizes, int n_in,
                              void* d_out, int out_size, void* d_ws, size_t ws_size,
                              hipStream_t stream) {
    const float* x  = (const float*)d_in[0];
    const int*   ei = (const int*)d_in[1];
    const float* W1 = (const float*)d_in[2];
    const float* b1 = (const float*)d_in[3];
    const float* Wq = (const float*)d_in[4];
    const float* bq = (const float*)d_in[5];
    const float* Wk = (const float*)d_in[6];
    const float* bk = (const float*)d_in[7];
    const float* Wv = (const float*)d_in[8];
    const float* bv = (const float*)d_in[9];
    const float* Ws = (const float*)d_in[10];
    const float* bs = (const float*)d_in[11];
    const float* W2 = (const float*)d_in[12];
    const float* b2 = (const float*)d_in[13];
    float* out = (float*)d_out;

    const int N = in_sizes[0] / 256;
    const int E = in_sizes[1] / 2;

    // d_out staging (all dead before k_agg2gemm2 rewrites out):
    //   kvb  bf16 [N][128] (K||V)      25.6 MB
    //   xw1b bf16 [N][64]              12.8 MB
    //   B    f32  [N][64] (h1 then q)  25.6 MB   -> 64 MB <= out 100 MB
    char* ob = (char*)d_out;
    u16*   kvb  = (u16*)ob;
    u16*   xw1b = (u16*)(ob + (size_t)N * 128 * 2);
    float* B    = (float*)(ob + (size_t)N * 128 * 2 + (size_t)N * 64 * 2);

    // d_ws (~33 MB): CSR machinery + packed edge data + h2 (bf16)
    char* p = (char*)d_ws;
    auto alloc = [&](size_t bytes) { char* r = p; p += (bytes + 255) & ~(size_t)255; return r; };
    int*   cnt    = (int*)alloc((size_t)N * 4);        // becomes scatter cursor
    int*   rowptr = (int*)alloc((size_t)(N + 1) * 4);
    int*   bsums  = (int*)alloc(1024);
    int*   csr    = (int*)alloc((size_t)E * 4);
    int2*  edat   = (int2*)alloc((size_t)E * 8);
    float* dinv   = (float*)alloc((size_t)N * 4);
    u16*   h2b    = (u16*)alloc((size_t)N * 64 * 2);

    const int NB = (N + 1023) / 1024;

    hipMemsetAsync(cnt, 0, (size_t)N * 4, stream);
    k_hist<<<(E + 255) / 256, 256, 0, stream>>>(ei + E, cnt, E);
    k_blocksum<<<NB, 256, 0, stream>>>(cnt, bsums, N);
    k_scan_bsums<<<1, 64, 0, stream>>>(bsums, NB);
    k_scan_final<<<NB, 256, 0, stream>>>(cnt, bsums, rowptr, dinv, N, E);
    k_scatter<<<(E + 255) / 256, 256, 0, stream>>>(ei, cnt, dinv, csr, edat, E);

    k_gemm1<<<(N + 7) / 8, 256, 0, stream>>>(x, W1, xw1b, N);
    k_agg1<<<(N + 3) / 4, 256, 0, stream>>>(xw1b, edat, rowptr, dinv, b1, B, N);
    k_lin_qkvs<<<(N + 7) / 8, 256, 0, stream>>>(B, Wq, bq, Wk, bk, Wv, bv, Ws, bs, kvb, h2b, N);
    k_attn<<<(N + 3) / 4, 256, 0, stream>>>(B, kvb, csr, rowptr, h2b, N);
    k_agg2gemm2<<<(N + 15) / 16, 256, 0, stream>>>(h2b, edat, rowptr, dinv, W2, b2, out, N);
}

// Round 10
// 582.006 us; speedup vs baseline: 2.1564x; 1.1041x over previous
//
#include <hip/hip_runtime.h>
#include <hip/hip_bf16.h>

typedef unsigned short u16;
typedef unsigned int u32;

__device__ __forceinline__ float bl(u32 u) { union { u32 i; float f; } c; c.i = u << 16; return c.f; }
__device__ __forceinline__ float bh(u32 u) { union { u32 i; float f; } c; c.i = u & 0xffff0000u; return c.f; }
__device__ __forceinline__ u16 f2us(float f) {
    __hip_bfloat16 h = __float2bfloat16(f);
    return *reinterpret_cast<u16*>(&h);
}
__device__ __forceinline__ u32 pk2(float a, float b) {
    return (u32)f2us(a) | ((u32)f2us(b) << 16);
}
__device__ __forceinline__ void up8(uint4 u, float* f) {
    f[0] = bl(u.x); f[1] = bh(u.x); f[2] = bl(u.y); f[3] = bh(u.y);
    f[4] = bl(u.z); f[5] = bh(u.z); f[6] = bl(u.w); f[7] = bh(u.w);
}

typedef short bf16x8 __attribute__((ext_vector_type(8)));
typedef float f32x4 __attribute__((ext_vector_type(4)));

// ---------------- CSR build ----------------
__global__ void k_hist(const int* __restrict__ dst, int* __restrict__ cnt, int E) {
    int e = blockIdx.x * 256 + threadIdx.x;
    if (e < E) atomicAdd(&cnt[dst[e]], 1);
}

__global__ void k_blocksum(const int* __restrict__ cnt, int* __restrict__ bsums, int n) {
    int base = blockIdx.x * 1024;
    int t = threadIdx.x;
    int s = 0;
    for (int j = t; j < 1024; j += 256) { int i = base + j; if (i < n) s += cnt[i]; }
    __shared__ int red[256];
    red[t] = s; __syncthreads();
    for (int off = 128; off > 0; off >>= 1) { if (t < off) red[t] += red[t + off]; __syncthreads(); }
    if (t == 0) bsums[blockIdx.x] = red[0];
}

// parallel exclusive scan of bsums (nb <= 1024), one block of 256 threads
__global__ void k_scan_bsums(int* __restrict__ bsums, int nb) {
    int t = threadIdx.x;
    int i0 = t * 4;
    int v[4]; int s = 0;
    #pragma unroll
    for (int j = 0; j < 4; j++) { v[j] = (i0 + j < nb) ? bsums[i0 + j] : 0; s += v[j]; }
    __shared__ int sc[256];
    sc[t] = s; __syncthreads();
    int acc = s;
    for (int off = 1; off < 256; off <<= 1) {
        int add = (t >= off) ? sc[t - off] : 0;
        __syncthreads();
        acc += add; sc[t] = acc;
        __syncthreads();
    }
    int run = acc - s;
    #pragma unroll
    for (int j = 0; j < 4; j++) {
        if (i0 + j < nb) { bsums[i0 + j] = run; run += v[j]; }
    }
}

__global__ void k_scan_final(int* __restrict__ cnt, const int* __restrict__ bsums,
                             int* __restrict__ rowptr, float* __restrict__ dinv, int n, int E) {
    int base = blockIdx.x * 1024;
    int t = threadIdx.x;
    int i0 = base + t * 4;
    int v[4]; int s = 0;
    for (int j = 0; j < 4; j++) { int i = i0 + j; v[j] = (i < n) ? cnt[i] : 0; s += v[j]; }
    __shared__ int sc[256];
    sc[t] = s; __syncthreads();
    int acc = s;
    for (int off = 1; off < 256; off <<= 1) {
        int add = (t >= off) ? sc[t - off] : 0;
        __syncthreads();
        acc += add; sc[t] = acc;
        __syncthreads();
    }
    int run = acc - s + bsums[blockIdx.x];
    for (int j = 0; j < 4; j++) {
        int i = i0 + j;
        if (i < n) {
            rowptr[i] = run;
            dinv[i] = rsqrtf((float)(v[j] + 1));
            cnt[i] = run;   // cursor for scatter
            run += v[j];
        }
    }
    if (blockIdx.x == 0 && t == 0) rowptr[n] = E;
}

// csr (4B, for attn) + edat int2 {src, wnorm} (8B, for GCN aggs)
__global__ void k_scatter(const int* __restrict__ ei, int* __restrict__ cursor,
                          const float* __restrict__ dinv,
                          int* __restrict__ csr, int2* __restrict__ edat, int E) {
    int e = blockIdx.x * 256 + threadIdx.x;
    if (e < E) {
        int s = ei[e], d = ei[E + e];
        int pos = atomicAdd(&cursor[d], 1);
        csr[pos] = s;
        edat[pos] = make_int2(s, __float_as_int(dinv[s] * dinv[d]));
    }
}

// ---------------- W2 -> bf16 preconvert (64x256) ----------------
__global__ void k_w2cast(const float* __restrict__ W2, u16* __restrict__ W2b) {
    int i = blockIdx.x * 256 + threadIdx.x;
    if (i < 64 * 256) W2b[i] = f2us(W2[i]);
}

// ---------------- GEMM1: xw1 = x @ W1 -> xw1b (bf16 [N][64]) ----------------
__global__ __launch_bounds__(256) void k_gemm1(const float* __restrict__ x,
                                               const float* __restrict__ W1,
                                               u16* __restrict__ xw1b, int n) {
    int w = threadIdx.x >> 6, l = threadIdx.x & 63;
    int n0 = blockIdx.x * 8 + w * 2, n1 = n0 + 1;
    __shared__ float xs[8][256];
    if (n0 < n) {
        float4 u = ((const float4*)(x + (size_t)n0 * 256))[l];
        xs[w * 2][l * 4 + 0] = u.x; xs[w * 2][l * 4 + 1] = u.y;
        xs[w * 2][l * 4 + 2] = u.z; xs[w * 2][l * 4 + 3] = u.w;
    }
    if (n1 < n) {
        float4 u = ((const float4*)(x + (size_t)n1 * 256))[l];
        xs[w * 2 + 1][l * 4 + 0] = u.x; xs[w * 2 + 1][l * 4 + 1] = u.y;
        xs[w * 2 + 1][l * 4 + 2] = u.z; xs[w * 2 + 1][l * 4 + 3] = u.w;
    }
    __syncthreads();
    if (n0 >= n) return;
    float a0 = 0.f, a1 = 0.f;
    #pragma unroll 8
    for (int k = 0; k < 256; k++) {
        float wv = W1[k * 64 + l];
        a0 += xs[w * 2][k] * wv;
        a1 += xs[w * 2 + 1][k] * wv;
    }
    xw1b[(size_t)n0 * 64 + l] = f2us(a0);
    if (n1 < n) xw1b[(size_t)n1 * 64 + l] = f2us(a1);
}

// ------- GCN1 aggregate: h1 = relu(Anorm*xw1 + b1) -> B (f32). 8x8 groups, 16 edges in flight. -------
__global__ __launch_bounds__(256) void k_agg1(const u16* __restrict__ xw1b,
                                              const int2* __restrict__ edat,
                                              const int* __restrict__ rowptr,
                                              const float* __restrict__ dinv,
                                              const float* __restrict__ b1,
                                              float* __restrict__ B, int n) {
    int t = threadIdx.x;
    int w = t >> 6, l = t & 63, g = l >> 3, li = l & 7;
    int node = blockIdx.x * 4 + w;
    if (node >= n) return;
    int beg = rowptr[node], end = rowptr[node + 1];
    float a0[8], a1[8];
    #pragma unroll
    for (int j = 0; j < 8; j++) { a0[j] = 0.f; a1[j] = 0.f; }
    for (int e0 = beg; e0 < end; e0 += 16) {
        int eA = e0 + g, eB = e0 + 8 + g;
        bool vA = (eA < end), vB = (eB < end);
        int2 dA = vA ? edat[eA] : make_int2(0, 0);
        int2 dB = vB ? edat[eB] : make_int2(0, 0);
        uint4 uA = *(const uint4*)(xw1b + (size_t)dA.x * 64 + li * 8);
        uint4 uB = *(const uint4*)(xw1b + (size_t)dB.x * 64 + li * 8);
        float wA = __int_as_float(dA.y), wB = __int_as_float(dB.y);
        float fA[8]; up8(uA, fA);
        float fB[8]; up8(uB, fB);
        #pragma unroll
        for (int j = 0; j < 8; j++) { a0[j] += fA[j] * wA; a1[j] += fB[j] * wB; }
    }
    #pragma unroll
    for (int j = 0; j < 8; j++) a0[j] += a1[j];
    #pragma unroll
    for (int off = 8; off <= 32; off <<= 1)
        #pragma unroll
        for (int j = 0; j < 8; j++) a0[j] += __shfl_xor(a0[j], off);
    if (g == 0) {
        float di = dinv[node], di2 = di * di;
        uint4 u = *(const uint4*)(xw1b + (size_t)node * 64 + li * 8);
        float sf[8]; up8(u, sf);
        float4 bv0 = *(const float4*)(b1 + li * 8);
        float4 bv1 = *(const float4*)(b1 + li * 8 + 4);
        float bb[8] = {bv0.x, bv0.y, bv0.z, bv0.w, bv1.x, bv1.y, bv1.z, bv1.w};
        float r[8];
        #pragma unroll
        for (int j = 0; j < 8; j++) r[j] = fmaxf(a0[j] + sf[j] * di2 + bb[j], 0.f);
        float* dst = B + (size_t)node * 64 + li * 8;
        *(float4*)dst = make_float4(r[0], r[1], r[2], r[3]);
        *(float4*)(dst + 4) = make_float4(r[4], r[5], r[6], r[7]);
    }
}

// ------- lin_qkvs: q (f32, in-place over h1 in B), K||V -> kvb (bf16), skip -> h2b (bf16) -------
__global__ __launch_bounds__(256) void k_lin_qkvs(float* __restrict__ B,
                                                  const float* __restrict__ Wq, const float* __restrict__ bq,
                                                  const float* __restrict__ Wk, const float* __restrict__ bk,
                                                  const float* __restrict__ Wv, const float* __restrict__ bv,
                                                  const float* __restrict__ Ws, const float* __restrict__ bs,
                                                  u16* __restrict__ kvb, u16* __restrict__ h2b, int n) {
    int w = threadIdx.x >> 6, l = threadIdx.x & 63;
    int n0 = blockIdx.x * 8 + w * 2, n1 = n0 + 1;
    __shared__ float hs[8][64];
    if (n0 < n) hs[w * 2][l] = B[(size_t)n0 * 64 + l];
    if (n1 < n) hs[w * 2 + 1][l] = B[(size_t)n1 * 64 + l];
    __syncthreads();
    if (n0 >= n) return;
    float q0 = 0, k0 = 0, v0 = 0, s0 = 0, q1 = 0, k1 = 0, v1 = 0, s1 = 0;
    #pragma unroll 4
    for (int kk = 0; kk < 64; kk++) {
        float h0 = hs[w * 2][kk], h1v = hs[w * 2 + 1][kk];
        float wq = Wq[kk * 64 + l]; q0 += h0 * wq; q1 += h1v * wq;
        float wk = Wk[kk * 64 + l]; k0 += h0 * wk; k1 += h1v * wk;
        float wv = Wv[kk * 64 + l]; v0 += h0 * wv; v1 += h1v * wv;
        float ws_ = Ws[kk * 64 + l]; s0 += h0 * ws_; s1 += h1v * ws_;
    }
    float bql = bq[l], bkl = bk[l], bvl = bv[l], bsl = bs[l];
    kvb[(size_t)n0 * 128 + l]      = f2us(k0 + bkl);
    kvb[(size_t)n0 * 128 + 64 + l] = f2us(v0 + bvl);
    B[(size_t)n0 * 64 + l]         = q0 + bql;       // in-place: own row only
    h2b[(size_t)n0 * 64 + l]       = f2us(s0 + bsl); // skip pre-stored
    if (n1 < n) {
        kvb[(size_t)n1 * 128 + l]      = f2us(k1 + bkl);
        kvb[(size_t)n1 * 128 + 64 + l] = f2us(v1 + bvl);
        B[(size_t)n1 * 64 + l]         = q1 + bql;
        h2b[(size_t)n1 * 64 + l]       = f2us(s1 + bsl);
    }
}

// ------- attention: warp/node, 8x8 groups, 16 edges in flight (dual softmax state) -------
__global__ __launch_bounds__(256) void k_attn(const float* __restrict__ B,
                                              const u16* __restrict__ kvb,
                                              const int* __restrict__ csr,
                                              const int* __restrict__ rowptr,
                                              u16* __restrict__ h2b, int n) {
    int t = threadIdx.x;
    int w = t >> 6, l = t & 63, g = l >> 3, li = l & 7;
    int node = blockIdx.x * 4 + w;
    if (node >= n) return;
    const float* qp = B + (size_t)node * 64 + li * 8;
    float4 qa = *(const float4*)qp;
    float4 qb = *(const float4*)(qp + 4);
    float q[8] = {qa.x, qa.y, qa.z, qa.w, qb.x, qb.y, qb.z, qb.w};
    int beg = rowptr[node], end = rowptr[node + 1];
    float mA = -1e30f, denA = 0.f, mB = -1e30f, denB = 0.f;
    float accA[8], accB[8];
    #pragma unroll
    for (int j = 0; j < 8; j++) { accA[j] = 0.f; accB[j] = 0.f; }
    for (int e0 = beg; e0 < end; e0 += 16) {
        int eA = e0 + g, eB = e0 + 8 + g;
        bool vA = (eA < end), vB = (eB < end);
        int sA = vA ? csr[eA] : 0;
        int sB = vB ? csr[eB] : 0;
        const u16* rowA = kvb + (size_t)sA * 128;
        const u16* rowB = kvb + (size_t)sB * 128;
        uint4 kuA = *(const uint4*)(rowA + li * 8);
        uint4 vuA = *(const uint4*)(rowA + 64 + li * 8);
        uint4 kuB = *(const uint4*)(rowB + li * 8);
        uint4 vuB = *(const uint4*)(rowB + 64 + li * 8);
        float kf[8], vf[8];
        // state A
        up8(kuA, kf); up8(vuA, vf);
        float dA = 0.f;
        #pragma unroll
        for (int j = 0; j < 8; j++) dA += q[j] * kf[j];
        dA += __shfl_xor(dA, 1);
        dA += __shfl_xor(dA, 2);
        dA += __shfl_xor(dA, 4);
        float logitA = vA ? dA * 0.125f : -1e30f;
        float nmA = fmaxf(mA, logitA);
        float rA = __expf(mA - nmA);
        float pA = vA ? __expf(logitA - nmA) : 0.f;
        denA = denA * rA + pA;
        #pragma unroll
        for (int j = 0; j < 8; j++) accA[j] = accA[j] * rA + pA * vf[j];
        mA = nmA;
        // state B
        up8(kuB, kf); up8(vuB, vf);
        float dB = 0.f;
        #pragma unroll
        for (int j = 0; j < 8; j++) dB += q[j] * kf[j];
        dB += __shfl_xor(dB, 1);
        dB += __shfl_xor(dB, 2);
        dB += __shfl_xor(dB, 4);
        float logitB = vB ? dB * 0.125f : -1e30f;
        float nmB = fmaxf(mB, logitB);
        float rB = __expf(mB - nmB);
        float pB = vB ? __expf(logitB - nmB) : 0.f;
        denB = denB * rB + pB;
        #pragma unroll
        for (int j = 0; j < 8; j++) accB[j] = accB[j] * rB + pB * vf[j];
        mB = nmB;
    }
    // merge A,B
    float m = fmaxf(mA, mB);
    float rA = __expf(mA - m), rB = __expf(mB - m);
    float den = denA * rA + denB * rB;
    float acc[8];
    #pragma unroll
    for (int j = 0; j < 8; j++) acc[j] = accA[j] * rA + accB[j] * rB;
    // merge 8 group states: butterfly xor 8,16,32
    #pragma unroll
    for (int off = 8; off <= 32; off <<= 1) {
        float mo = __shfl_xor(m, off);
        float deno = __shfl_xor(den, off);
        float nm = fmaxf(m, mo);
        float r = __expf(m - nm), ro = __expf(mo - nm);
        den = den * r + deno * ro;
        #pragma unroll
        for (int j = 0; j < 8; j++) {
            float ao = __shfl_xor(acc[j], off);
            acc[j] = acc[j] * r + ao * ro;
        }
        m = nm;
    }
    if (g == 0) {
        float inv = (den > 0.f) ? 1.f / den : 0.f;
        u16* hp = h2b + (size_t)node * 64 + li * 8;
        uint4 su = *(const uint4*)hp;    // skip pre-stored by lin_qkvs
        float sk[8]; up8(su, sk);
        float o[8];
        #pragma unroll
        for (int j = 0; j < 8; j++) o[j] = acc[j] * inv + sk[j];
        uint4 ou;
        ou.x = pk2(o[0], o[1]); ou.y = pk2(o[2], o[3]);
        ou.z = pk2(o[4], o[5]); ou.w = pk2(o[6], o[7]);
        *(uint4*)hp = ou;
    }
}

// ------- fused GCN2 aggregate + MFMA GEMM2: out = (Anorm*h2) @ W2 + b2 -------
// Gather phase -> ag (bf16 LDS, pitch 72); MFMA 16x16x32_bf16 epilogue.
__global__ __launch_bounds__(256) void k_agg2gemm2(const u16* __restrict__ h2b,
                                                   const int2* __restrict__ edat,
                                                   const int* __restrict__ rowptr,
                                                   const float* __restrict__ dinv,
                                                   const u16* __restrict__ W2b,
                                                   const float* __restrict__ b2,
                                                   float* __restrict__ out, int n) {
    __shared__ u16 ag[16][72];   // bf16 tile, padded pitch (144B rows, 16B-aligned frags)
    int t = threadIdx.x, w = t >> 6, l = t & 63, g = l >> 3, li = l & 7;
    int base = blockIdx.x * 16;
    for (int i = w; i < 16; i += 4) {
        int node = base + i;
        float a0[8], a1[8];
        #pragma unroll
        for (int j = 0; j < 8; j++) { a0[j] = 0.f; a1[j] = 0.f; }
        if (node < n) {
            int beg = rowptr[node], end = rowptr[node + 1];
            for (int e0 = beg; e0 < end; e0 += 16) {
                int eA = e0 + g, eB = e0 + 8 + g;
                bool vA = (eA < end), vB = (eB < end);
                int2 dA = vA ? edat[eA] : make_int2(0, 0);
                int2 dB = vB ? edat[eB] : make_int2(0, 0);
                uint4 uA = *(const uint4*)(h2b + (size_t)dA.x * 64 + li * 8);
                uint4 uB = *(const uint4*)(h2b + (size_t)dB.x * 64 + li * 8);
                float wA = __int_as_float(dA.y), wB = __int_as_float(dB.y);
                float fA[8]; up8(uA, fA);
                float fB[8]; up8(uB, fB);
                #pragma unroll
                for (int j = 0; j < 8; j++) { a0[j] += fA[j] * wA; a1[j] += fB[j] * wB; }
            }
        }
        #pragma unroll
        for (int j = 0; j < 8; j++) a0[j] += a1[j];
        #pragma unroll
        for (int off = 8; off <= 32; off <<= 1)
            #pragma unroll
            for (int j = 0; j < 8; j++) a0[j] += __shfl_xor(a0[j], off);
        if (g == 0) {
            if (node < n) {
                float di = dinv[node], di2 = di * di;
                uint4 u = *(const uint4*)(h2b + (size_t)node * 64 + li * 8);
                float sf[8]; up8(u, sf);
                #pragma unroll
                for (int j = 0; j < 8; j++) a0[j] += sf[j] * di2;
            }
            uint4 ou;
            ou.x = pk2(a0[0], a0[1]); ou.y = pk2(a0[2], a0[3]);
            ou.z = pk2(a0[4], a0[5]); ou.w = pk2(a0[6], a0[7]);
            *(uint4*)&ag[i][li * 8] = ou;
        }
    }
    __syncthreads();
    // ---- MFMA phase: C[16 x 256] = ag[16 x 64] @ W2b[64 x 256], f32 out + bias ----
    int c = l & 15;           // A-row / B-col / D-col
    int kg = l >> 4;          // k-group 0..3
    bf16x8 alo = *(const bf16x8*)&ag[c][kg * 8];
    bf16x8 ahi = *(const bf16x8*)&ag[c][32 + kg * 8];
    #pragma unroll
    for (int ti = 0; ti < 4; ti++) {
        int ct = w * 4 + ti;
        int col = ct * 16 + c;
        bf16x8 blo, bhi;
        #pragma unroll
        for (int j = 0; j < 8; j++) {
            blo[j] = (short)W2b[(kg * 8 + j) * 256 + col];
            bhi[j] = (short)W2b[(32 + kg * 8 + j) * 256 + col];
        }
        f32x4 acc = {0.f, 0.f, 0.f, 0.f};
        acc = __builtin_amdgcn_mfma_f32_16x16x32_bf16(alo, blo, acc, 0, 0, 0);
        acc = __builtin_amdgcn_mfma_f32_16x16x32_bf16(ahi, bhi, acc, 0, 0, 0);
        float bias = b2[col];
        #pragma unroll
        for (int r = 0; r < 4; r++) {
            int node = base + kg * 4 + r;
            if (node < n) out[(size_t)node * 256 + col] = acc[r] + bias;
        }
    }
}

extern "C" void kernel_launch(void* const* d_in, const int* in_sizes, int n_in,
                              void* d_out, int out_size, void* d_ws, size_t ws_size,
                              hipStream_t stream) {
    const float* x  = (const float*)d_in[0];
    const int*   ei = (const int*)d_in[1];
    const float* W1 = (const float*)d_in[2];
    const float* b1 = (const float*)d_in[3];
    const float* Wq = (const float*)d_in[4];
    const float* bq = (const float*)d_in[5];
    const float* Wk = (const float*)d_in[6];
    const float* bk = (const float*)d_in[7];
    const float* Wv = (const float*)d_in[8];
    const float* bv = (const float*)d_in[9];
    const float* Ws = (const float*)d_in[10];
    const float* bs = (const float*)d_in[11];
    const float* W2 = (const float*)d_in[12];
    const float* b2 = (const float*)d_in[13];
    float* out = (float*)d_out;

    const int N = in_sizes[0] / 256;
    const int E = in_sizes[1] / 2;

    // d_out staging (all dead before k_agg2gemm2 rewrites out):
    //   kvb  bf16 [N][128] (K||V)      25.6 MB
    //   xw1b bf16 [N][64]              12.8 MB
    //   B    f32  [N][64] (h1 then q)  25.6 MB   -> 64 MB <= out 100 MB
    char* ob = (char*)d_out;
    u16*   kvb  = (u16*)ob;
    u16*   xw1b = (u16*)(ob + (size_t)N * 128 * 2);
    float* B    = (float*)(ob + (size_t)N * 128 * 2 + (size_t)N * 64 * 2);

    // d_ws (~33 MB): CSR machinery + packed edge data + h2 (bf16) + W2 bf16
    char* p = (char*)d_ws;
    auto alloc = [&](size_t bytes) { char* r = p; p += (bytes + 255) & ~(size_t)255; return r; };
    int*   cnt    = (int*)alloc((size_t)N * 4);        // becomes scatter cursor
    int*   rowptr = (int*)alloc((size_t)(N + 1) * 4);
    int*   bsums  = (int*)alloc(4096);
    int*   csr    = (int*)alloc((size_t)E * 4);
    int2*  edat   = (int2*)alloc((size_t)E * 8);
    float* dinv   = (float*)alloc((size_t)N * 4);
    u16*   h2b    = (u16*)alloc((size_t)N * 64 * 2);
    u16*   W2b    = (u16*)alloc((size_t)64 * 256 * 2);

    const int NB = (N + 1023) / 1024;

    hipMemsetAsync(cnt, 0, (size_t)N * 4, stream);
    k_hist<<<(E + 255) / 256, 256, 0, stream>>>(ei + E, cnt, E);
    k_blocksum<<<NB, 256, 0, stream>>>(cnt, bsums, N);
    k_scan_bsums<<<1, 256, 0, stream>>>(bsums, NB);
    k_scan_final<<<NB, 256, 0, stream>>>(cnt, bsums, rowptr, dinv, N, E);
    k_scatter<<<(E + 255) / 256, 256, 0, stream>>>(ei, cnt, dinv, csr, edat, E);
    k_w2cast<<<64, 256, 0, stream>>>(W2, W2b);

    k_gemm1<<<(N + 7) / 8, 256, 0, stream>>>(x, W1, xw1b, N);
    k_agg1<<<(N + 3) / 4, 256, 0, stream>>>(xw1b, edat, rowptr, dinv, b1, B, N);
    k_lin_qkvs<<<(N + 7) / 8, 256, 0, stream>>>(B, Wq, bq, Wk, bk, Wv, bv, Ws, bs, kvb, h2b, N);
    k_attn<<<(N + 3) / 4, 256, 0, stream>>>(B, kvb, csr, rowptr, h2b, N);
    k_agg2gemm2<<<(N + 15) / 16, 256, 0, stream>>>(h2b, edat, rowptr, dinv, W2b, b2, out, N);
}

// Round 12
// 459.043 us; speedup vs baseline: 2.7340x; 1.2679x over previous
//
#include <hip/hip_runtime.h>
#include <hip/hip_bf16.h>

typedef unsigned short u16;
typedef unsigned int u32;

__device__ __forceinline__ float bl(u32 u) { union { u32 i; float f; } c; c.i = u << 16; return c.f; }
__device__ __forceinline__ float bh(u32 u) { union { u32 i; float f; } c; c.i = u & 0xffff0000u; return c.f; }
__device__ __forceinline__ u16 f2us(float f) {
    __hip_bfloat16 h = __float2bfloat16(f);
    return *reinterpret_cast<u16*>(&h);
}
__device__ __forceinline__ u32 pk2(float a, float b) {
    return (u32)f2us(a) | ((u32)f2us(b) << 16);
}
__device__ __forceinline__ void up8(uint4 u, float* f) {
    f[0] = bl(u.x); f[1] = bh(u.x); f[2] = bl(u.y); f[3] = bh(u.y);
    f[4] = bl(u.z); f[5] = bh(u.z); f[6] = bl(u.w); f[7] = bh(u.w);
}

typedef short bf16x8 __attribute__((ext_vector_type(8)));
typedef float f32x4 __attribute__((ext_vector_type(4)));

// ---------------- CSR build ----------------
__global__ void k_hist(const int* __restrict__ dst, int* __restrict__ cnt, int E) {
    int e = blockIdx.x * 256 + threadIdx.x;
    if (e < E) atomicAdd(&cnt[dst[e]], 1);
}

__global__ void k_blocksum(const int* __restrict__ cnt, int* __restrict__ bsums, int n) {
    int base = blockIdx.x * 1024;
    int t = threadIdx.x;
    int s = 0;
    for (int j = t; j < 1024; j += 256) { int i = base + j; if (i < n) s += cnt[i]; }
    __shared__ int red[256];
    red[t] = s; __syncthreads();
    for (int off = 128; off > 0; off >>= 1) { if (t < off) red[t] += red[t + off]; __syncthreads(); }
    if (t == 0) bsums[blockIdx.x] = red[0];
}

// parallel exclusive scan of bsums (nb <= 1024), one block of 256 threads
__global__ void k_scan_bsums(int* __restrict__ bsums, int nb) {
    int t = threadIdx.x;
    int i0 = t * 4;
    int v[4]; int s = 0;
    #pragma unroll
    for (int j = 0; j < 4; j++) { v[j] = (i0 + j < nb) ? bsums[i0 + j] : 0; s += v[j]; }
    __shared__ int sc[256];
    sc[t] = s; __syncthreads();
    int acc = s;
    for (int off = 1; off < 256; off <<= 1) {
        int add = (t >= off) ? sc[t - off] : 0;
        __syncthreads();
        acc += add; sc[t] = acc;
        __syncthreads();
    }
    int run = acc - s;
    #pragma unroll
    for (int j = 0; j < 4; j++) {
        if (i0 + j < nb) { bsums[i0 + j] = run; run += v[j]; }
    }
}

__global__ void k_scan_final(int* __restrict__ cnt, const int* __restrict__ bsums,
                             int* __restrict__ rowptr, float* __restrict__ dinv, int n, int E) {
    int base = blockIdx.x * 1024;
    int t = threadIdx.x;
    int i0 = base + t * 4;
    int v[4]; int s = 0;
    for (int j = 0; j < 4; j++) { int i = i0 + j; v[j] = (i < n) ? cnt[i] : 0; s += v[j]; }
    __shared__ int sc[256];
    sc[t] = s; __syncthreads();
    int acc = s;
    for (int off = 1; off < 256; off <<= 1) {
        int add = (t >= off) ? sc[t - off] : 0;
        __syncthreads();
        acc += add; sc[t] = acc;
        __syncthreads();
    }
    int run = acc - s + bsums[blockIdx.x];
    for (int j = 0; j < 4; j++) {
        int i = i0 + j;
        if (i < n) {
            rowptr[i] = run;
            dinv[i] = rsqrtf((float)(v[j] + 1));
            cnt[i] = run;   // cursor for scatter
            run += v[j];
        }
    }
    if (blockIdx.x == 0 && t == 0) rowptr[n] = E;
}

// csr (4B, for attn) + edat int2 {src, wnorm} (8B, for GCN aggs)
__global__ void k_scatter(const int* __restrict__ ei, int* __restrict__ cursor,
                          const float* __restrict__ dinv,
                          int* __restrict__ csr, int2* __restrict__ edat, int E) {
    int e = blockIdx.x * 256 + threadIdx.x;
    if (e < E) {
        int s = ei[e], d = ei[E + e];
        int pos = atomicAdd(&cursor[d], 1);
        csr[pos] = s;
        edat[pos] = make_int2(s, __float_as_int(dinv[s] * dinv[d]));
    }
}

// ---------------- weight preconversions ----------------
__global__ void k_w2cast(const float* __restrict__ W2, u16* __restrict__ W2b) {
    int i = blockIdx.x * 256 + threadIdx.x;
    if (i < 64 * 256) W2b[i] = f2us(W2[i]);
}

// W1 [256][64] f32 -> W1t [64 cols][256 k] bf16
__global__ void k_w1cast(const float* __restrict__ W1, u16* __restrict__ W1t) {
    int i = blockIdx.x * 256 + threadIdx.x;   // i = col*256 + k
    if (i < 64 * 256) {
        int col = i >> 8, k = i & 255;
        W1t[i] = f2us(W1[k * 64 + col]);
    }
}

// Wq|Wk|Wv|Ws [64][64] f32 -> Wcat [256 outcols][64 k] bf16
__global__ void k_wcat(const float* __restrict__ Wq, const float* __restrict__ Wk,
                       const float* __restrict__ Wv, const float* __restrict__ Ws,
                       u16* __restrict__ Wcat) {
    int i = blockIdx.x * 256 + threadIdx.x;   // i = col*64 + k
    if (i < 256 * 64) {
        int col = i >> 6, k = i & 63;
        int m = col >> 6, mc = col & 63;
        const float* src = (m == 0) ? Wq : (m == 1) ? Wk : (m == 2) ? Wv : Ws;
        Wcat[i] = f2us(src[k * 64 + mc]);
    }
}

// ---------------- GEMM1 (MFMA): xw1b = bf16(x) @ W1 ; 16 nodes/block ----------------
__global__ __launch_bounds__(256) void k_gemm1(const float* __restrict__ x,
                                               const u16* __restrict__ W1t,
                                               u16* __restrict__ xw1b, int n) {
    __shared__ u16 xs[16][264];    // pitch 528B: 16B-aligned frags, 2-way bank alias only
    int t = threadIdx.x, w = t >> 6, l = t & 63;
    int base = blockIdx.x * 16;
    // stage x tile -> bf16
    int row = t >> 4, seg = t & 15;
    int node = base + row;
    const float4* src = (const float4*)(x + (size_t)(node < n ? node : n - 1) * 256 + seg * 16);
    float4 f0 = src[0], f1 = src[1], f2 = src[2], f3 = src[3];
    uint4 o0, o1;
    o0.x = pk2(f0.x, f0.y); o0.y = pk2(f0.z, f0.w);
    o0.z = pk2(f1.x, f1.y); o0.w = pk2(f1.z, f1.w);
    o1.x = pk2(f2.x, f2.y); o1.y = pk2(f2.z, f2.w);
    o1.z = pk2(f3.x, f3.y); o1.w = pk2(f3.z, f3.w);
    u16* dst = &xs[row][seg * 16];
    *(uint4*)dst = o0; *(uint4*)(dst + 8) = o1;
    __syncthreads();
    int c = l & 15, kg = l >> 4;
    int col = w * 16 + c;
    f32x4 acc = {0.f, 0.f, 0.f, 0.f};
    #pragma unroll
    for (int kk = 0; kk < 8; kk++) {
        bf16x8 a = *(const bf16x8*)&xs[c][kk * 32 + kg * 8];
        bf16x8 b = *(const bf16x8*)&W1t[(size_t)col * 256 + kk * 32 + kg * 8];
        acc = __builtin_amdgcn_mfma_f32_16x16x32_bf16(a, b, acc, 0, 0, 0);
    }
    #pragma unroll
    for (int r = 0; r < 4; r++) {
        int nd = base + kg * 4 + r;
        if (nd < n) xw1b[(size_t)nd * 64 + col] = f2us(acc[r]);
    }
}

// ------- GCN1 aggregate: h1 = relu(Anorm*xw1 + b1) -> B (f32). 8x8 groups, 16 edges in flight. -------
__global__ __launch_bounds__(256) void k_agg1(const u16* __restrict__ xw1b,
                                              const int2* __restrict__ edat,
                                              const int* __restrict__ rowptr,
                                              const float* __restrict__ dinv,
                                              const float* __restrict__ b1,
                                              float* __restrict__ B, int n) {
    int t = threadIdx.x;
    int w = t >> 6, l = t & 63, g = l >> 3, li = l & 7;
    int node = blockIdx.x * 4 + w;
    if (node >= n) return;
    int beg = rowptr[node], end = rowptr[node + 1];
    float a0[8], a1[8];
    #pragma unroll
    for (int j = 0; j < 8; j++) { a0[j] = 0.f; a1[j] = 0.f; }
    for (int e0 = beg; e0 < end; e0 += 16) {
        int eA = e0 + g, eB = e0 + 8 + g;
        bool vA = (eA < end), vB = (eB < end);
        int2 dA = vA ? edat[eA] : make_int2(0, 0);
        int2 dB = vB ? edat[eB] : make_int2(0, 0);
        uint4 uA = *(const uint4*)(xw1b + (size_t)dA.x * 64 + li * 8);
        uint4 uB = *(const uint4*)(xw1b + (size_t)dB.x * 64 + li * 8);
        float wA = __int_as_float(dA.y), wB = __int_as_float(dB.y);
        float fA[8]; up8(uA, fA);
        float fB[8]; up8(uB, fB);
        #pragma unroll
        for (int j = 0; j < 8; j++) { a0[j] += fA[j] * wA; a1[j] += fB[j] * wB; }
    }
    #pragma unroll
    for (int j = 0; j < 8; j++) a0[j] += a1[j];
    #pragma unroll
    for (int off = 8; off <= 32; off <<= 1)
        #pragma unroll
        for (int j = 0; j < 8; j++) a0[j] += __shfl_xor(a0[j], off);
    if (g == 0) {
        float di = dinv[node], di2 = di * di;
        uint4 u = *(const uint4*)(xw1b + (size_t)node * 64 + li * 8);
        float sf[8]; up8(u, sf);
        float4 bv0 = *(const float4*)(b1 + li * 8);
        float4 bv1 = *(const float4*)(b1 + li * 8 + 4);
        float bb[8] = {bv0.x, bv0.y, bv0.z, bv0.w, bv1.x, bv1.y, bv1.z, bv1.w};
        float r[8];
        #pragma unroll
        for (int j = 0; j < 8; j++) r[j] = fmaxf(a0[j] + sf[j] * di2 + bb[j], 0.f);
        float* dst = B + (size_t)node * 64 + li * 8;
        *(float4*)dst = make_float4(r[0], r[1], r[2], r[3]);
        *(float4*)(dst + 4) = make_float4(r[4], r[5], r[6], r[7]);
    }
}

// ------- lin_qkvs (MFMA): [q|k|v|s] = h1 @ Wcat; q->B f32 in-place, k/v->kvb, s->h2b -------
__global__ __launch_bounds__(256) void k_lin_qkvs(float* __restrict__ B,
                                                  const u16* __restrict__ Wcat,
                                                  const float* __restrict__ bq, const float* __restrict__ bk,
                                                  const float* __restrict__ bv, const float* __restrict__ bs,
                                                  u16* __restrict__ kvb, u16* __restrict__ h2b, int n) {
    __shared__ u16 hs[16][72];    // pitch 144B: 16B-aligned frags
    int t = threadIdx.x, w = t >> 6, l = t & 63;
    int base = blockIdx.x * 16;
    int row = t >> 4, q4 = t & 15;
    int node = base + row;
    if (node < n) {
        float4 f = *(const float4*)(B + (size_t)node * 64 + q4 * 4);
        uint2 o; o.x = pk2(f.x, f.y); o.y = pk2(f.z, f.w);
        *(uint2*)&hs[row][q4 * 4] = o;
    }
    __syncthreads();
    int c = l & 15, kg = l >> 4;
    bf16x8 a0 = *(const bf16x8*)&hs[c][kg * 8];
    bf16x8 a1 = *(const bf16x8*)&hs[c][32 + kg * 8];
    #pragma unroll
    for (int ti = 0; ti < 4; ti++) {
        int col = (w * 4 + ti) * 16 + c;
        bf16x8 b0 = *(const bf16x8*)&Wcat[(size_t)col * 64 + kg * 8];
        bf16x8 b1 = *(const bf16x8*)&Wcat[(size_t)col * 64 + 32 + kg * 8];
        f32x4 acc = {0.f, 0.f, 0.f, 0.f};
        acc = __builtin_amdgcn_mfma_f32_16x16x32_bf16(a0, b0, acc, 0, 0, 0);
        acc = __builtin_amdgcn_mfma_f32_16x16x32_bf16(a1, b1, acc, 0, 0, 0);
        int m = col >> 6, mc = col & 63;
        float bias = ((m == 0) ? bq : (m == 1) ? bk : (m == 2) ? bv : bs)[mc];
        #pragma unroll
        for (int r = 0; r < 4; r++) {
            int nd = base + kg * 4 + r;
            if (nd < n) {
                float v = acc[r] + bias;
                if (m == 0)      B[(size_t)nd * 64 + mc] = v;          // q (f32)
                else if (m == 1) kvb[(size_t)nd * 128 + mc] = f2us(v); // k
                else if (m == 2) kvb[(size_t)nd * 128 + 64 + mc] = f2us(v); // v
                else             h2b[(size_t)nd * 64 + mc] = f2us(v);  // skip
            }
        }
    }
}

// ------- attention: warp/node, 8x8 groups, 16 edges in flight (dual softmax state) -------
__global__ __launch_bounds__(256) void k_attn(const float* __restrict__ B,
                                              const u16* __restrict__ kvb,
                                              const int* __restrict__ csr,
                                              const int* __restrict__ rowptr,
                                              u16* __restrict__ h2b, int n) {
    int t = threadIdx.x;
    int w = t >> 6, l = t & 63, g = l >> 3, li = l & 7;
    int node = blockIdx.x * 4 + w;
    if (node >= n) return;
    const float* qp = B + (size_t)node * 64 + li * 8;
    float4 qa = *(const float4*)qp;
    float4 qb = *(const float4*)(qp + 4);
    float q[8] = {qa.x, qa.y, qa.z, qa.w, qb.x, qb.y, qb.z, qb.w};
    int beg = rowptr[node], end = rowptr[node + 1];
    float mA = -1e30f, denA = 0.f, mB = -1e30f, denB = 0.f;
    float accA[8], accB[8];
    #pragma unroll
    for (int j = 0; j < 8; j++) { accA[j] = 0.f; accB[j] = 0.f; }
    for (int e0 = beg; e0 < end; e0 += 16) {
        int eA = e0 + g, eB = e0 + 8 + g;
        bool vA = (eA < end), vB = (eB < end);
        int sA = vA ? csr[eA] : 0;
        int sB = vB ? csr[eB] : 0;
        const u16* rowA = kvb + (size_t)sA * 128;
        const u16* rowB = kvb + (size_t)sB * 128;
        uint4 kuA = *(const uint4*)(rowA + li * 8);
        uint4 vuA = *(const uint4*)(rowA + 64 + li * 8);
        uint4 kuB = *(const uint4*)(rowB + li * 8);
        uint4 vuB = *(const uint4*)(rowB + 64 + li * 8);
        float kf[8], vf[8];
        // state A
        up8(kuA, kf); up8(vuA, vf);
        float dA = 0.f;
        #pragma unroll
        for (int j = 0; j < 8; j++) dA += q[j] * kf[j];
        dA += __shfl_xor(dA, 1);
        dA += __shfl_xor(dA, 2);
        dA += __shfl_xor(dA, 4);
        float logitA = vA ? dA * 0.125f : -1e30f;
        float nmA = fmaxf(mA, logitA);
        float rA = __expf(mA - nmA);
        float pA = vA ? __expf(logitA - nmA) : 0.f;
        denA = denA * rA + pA;
        #pragma unroll
        for (int j = 0; j < 8; j++) accA[j] = accA[j] * rA + pA * vf[j];
        mA = nmA;
        // state B
        up8(kuB, kf); up8(vuB, vf);
        float dB = 0.f;
        #pragma unroll
        for (int j = 0; j < 8; j++) dB += q[j] * kf[j];
        dB += __shfl_xor(dB, 1);
        dB += __shfl_xor(dB, 2);
        dB += __shfl_xor(dB, 4);
        float logitB = vB ? dB * 0.125f : -1e30f;
        float nmB = fmaxf(mB, logitB);
        float rB = __expf(mB - nmB);
        float pB = vB ? __expf(logitB - nmB) : 0.f;
        denB = denB * rB + pB;
        #pragma unroll
        for (int j = 0; j < 8; j++) accB[j] = accB[j] * rB + pB * vf[j];
        mB = nmB;
    }
    // merge A,B
    float m = fmaxf(mA, mB);
    float rA = __expf(mA - m), rB = __expf(mB - m);
    float den = denA * rA + denB * rB;
    float acc[8];
    #pragma unroll
    for (int j = 0; j < 8; j++) acc[j] = accA[j] * rA + accB[j] * rB;
    // merge 8 group states: butterfly xor 8,16,32
    #pragma unroll
    for (int off = 8; off <= 32; off <<= 1) {
        float mo = __shfl_xor(m, off);
        float deno = __shfl_xor(den, off);
        float nm = fmaxf(m, mo);
        float r = __expf(m - nm), ro = __expf(mo - nm);
        den = den * r + deno * ro;
        #pragma unroll
        for (int j = 0; j < 8; j++) {
            float ao = __shfl_xor(acc[j], off);
            acc[j] = acc[j] * r + ao * ro;
        }
        m = nm;
    }
    if (g == 0) {
        float inv = (den > 0.f) ? 1.f / den : 0.f;
        u16* hp = h2b + (size_t)node * 64 + li * 8;
        uint4 su = *(const uint4*)hp;    // skip pre-stored by lin_qkvs
        float sk[8]; up8(su, sk);
        float o[8];
        #pragma unroll
        for (int j = 0; j < 8; j++) o[j] = acc[j] * inv + sk[j];
        uint4 ou;
        ou.x = pk2(o[0], o[1]); ou.y = pk2(o[2], o[3]);
        ou.z = pk2(o[4], o[5]); ou.w = pk2(o[6], o[7]);
        *(uint4*)hp = ou;
    }
}

// ------- fused GCN2 aggregate + MFMA GEMM2: out = (Anorm*h2) @ W2 + b2 -------
__global__ __launch_bounds__(256) void k_agg2gemm2(const u16* __restrict__ h2b,
                                                   const int2* __restrict__ edat,
                                                   const int* __restrict__ rowptr,
                                                   const float* __restrict__ dinv,
                                                   const u16* __restrict__ W2b,
                                                   const float* __restrict__ b2,
                                                   float* __restrict__ out, int n) {
    __shared__ u16 ag[16][72];   // bf16 tile, padded pitch (144B rows, 16B-aligned frags)
    int t = threadIdx.x, w = t >> 6, l = t & 63, g = l >> 3, li = l & 7;
    int base = blockIdx.x * 16;
    for (int i = w; i < 16; i += 4) {
        int node = base + i;
        float a0[8], a1[8];
        #pragma unroll
        for (int j = 0; j < 8; j++) { a0[j] = 0.f; a1[j] = 0.f; }
        if (node < n) {
            int beg = rowptr[node], end = rowptr[node + 1];
            for (int e0 = beg; e0 < end; e0 += 16) {
                int eA = e0 + g, eB = e0 + 8 + g;
                bool vA = (eA < end), vB = (eB < end);
                int2 dA = vA ? edat[eA] : make_int2(0, 0);
                int2 dB = vB ? edat[eB] : make_int2(0, 0);
                uint4 uA = *(const uint4*)(h2b + (size_t)dA.x * 64 + li * 8);
                uint4 uB = *(const uint4*)(h2b + (size_t)dB.x * 64 + li * 8);
                float wA = __int_as_float(dA.y), wB = __int_as_float(dB.y);
                float fA[8]; up8(uA, fA);
                float fB[8]; up8(uB, fB);
                #pragma unroll
                for (int j = 0; j < 8; j++) { a0[j] += fA[j] * wA; a1[j] += fB[j] * wB; }
            }
        }
        #pragma unroll
        for (int j = 0; j < 8; j++) a0[j] += a1[j];
        #pragma unroll
        for (int off = 8; off <= 32; off <<= 1)
            #pragma unroll
            for (int j = 0; j < 8; j++) a0[j] += __shfl_xor(a0[j], off);
        if (g == 0) {
            if (node < n) {
                float di = dinv[node], di2 = di * di;
                uint4 u = *(const uint4*)(h2b + (size_t)node * 64 + li * 8);
                float sf[8]; up8(u, sf);
                #pragma unroll
                for (int j = 0; j < 8; j++) a0[j] += sf[j] * di2;
            }
            uint4 ou;
            ou.x = pk2(a0[0], a0[1]); ou.y = pk2(a0[2], a0[3]);
            ou.z = pk2(a0[4], a0[5]); ou.w = pk2(a0[6], a0[7]);
            *(uint4*)&ag[i][li * 8] = ou;
        }
    }
    __syncthreads();
    // ---- MFMA phase: C[16 x 256] = ag[16 x 64] @ W2b[64 x 256], f32 out + bias ----
    int c = l & 15;           // A-row / B-col / D-col
    int kg = l >> 4;          // k-group 0..3
    bf16x8 alo = *(const bf16x8*)&ag[c][kg * 8];
    bf16x8 ahi = *(const bf16x8*)&ag[c][32 + kg * 8];
    #pragma unroll
    for (int ti = 0; ti < 4; ti++) {
        int ct = w * 4 + ti;
        int col = ct * 16 + c;
        bf16x8 blo, bhi;
        #pragma unroll
        for (int j = 0; j < 8; j++) {
            blo[j] = (short)W2b[(kg * 8 + j) * 256 + col];
            bhi[j] = (short)W2b[(32 + kg * 8 + j) * 256 + col];
        }
        f32x4 acc = {0.f, 0.f, 0.f, 0.f};
        acc = __builtin_amdgcn_mfma_f32_16x16x32_bf16(alo, blo, acc, 0, 0, 0);
        acc = __builtin_amdgcn_mfma_f32_16x16x32_bf16(ahi, bhi, acc, 0, 0, 0);
        float bias = b2[col];
        #pragma unroll
        for (int r = 0; r < 4; r++) {
            int node = base + kg * 4 + r;
            if (node < n) out[(size_t)node * 256 + col] = acc[r] + bias;
        }
    }
}

extern "C" void kernel_launch(void* const* d_in, const int* in_sizes, int n_in,
                              void* d_out, int out_size, void* d_ws, size_t ws_size,
                              hipStream_t stream) {
    const float* x  = (const float*)d_in[0];
    const int*   ei = (const int*)d_in[1];
    const float* W1 = (const float*)d_in[2];
    const float* b1 = (const float*)d_in[3];
    const float* Wq = (const float*)d_in[4];
    const float* bq = (const float*)d_in[5];
    const float* Wk = (const float*)d_in[6];
    const float* bk = (const float*)d_in[7];
    const float* Wv = (const float*)d_in[8];
    const float* bv = (const float*)d_in[9];
    const float* Ws = (const float*)d_in[10];
    const float* bs = (const float*)d_in[11];
    const float* W2 = (const float*)d_in[12];
    const float* b2 = (const float*)d_in[13];
    float* out = (float*)d_out;

    const int N = in_sizes[0] / 256;
    const int E = in_sizes[1] / 2;

    // d_out staging (all dead before k_agg2gemm2 rewrites out):
    //   kvb  bf16 [N][128] (K||V)      25.6 MB
    //   xw1b bf16 [N][64]              12.8 MB
    //   B    f32  [N][64] (h1 then q)  25.6 MB   -> 64 MB <= out 100 MB
    char* ob = (char*)d_out;
    u16*   kvb  = (u16*)ob;
    u16*   xw1b = (u16*)(ob + (size_t)N * 128 * 2);
    float* B    = (float*)(ob + (size_t)N * 128 * 2 + (size_t)N * 64 * 2);

    // d_ws (~33 MB): CSR machinery + packed edge data + h2 (bf16) + weight casts
    char* p = (char*)d_ws;
    auto alloc = [&](size_t bytes) { char* r = p; p += (bytes + 255) & ~(size_t)255; return r; };
    int*   cnt    = (int*)alloc((size_t)N * 4);        // becomes scatter cursor
    int*   rowptr = (int*)alloc((size_t)(N + 1) * 4);
    int*   bsums  = (int*)alloc(4096);
    int*   csr    = (int*)alloc((size_t)E * 4);
    int2*  edat   = (int2*)alloc((size_t)E * 8);
    float* dinv   = (float*)alloc((size_t)N * 4);
    u16*   h2b    = (u16*)alloc((size_t)N * 64 * 2);
    u16*   W2b    = (u16*)alloc((size_t)64 * 256 * 2);
    u16*   W1t    = (u16*)alloc((size_t)64 * 256 * 2);
    u16*   Wcat   = (u16*)alloc((size_t)256 * 64 * 2);

    const int NB = (N + 1023) / 1024;

    hipMemsetAsync(cnt, 0, (size_t)N * 4, stream);
    k_hist<<<(E + 255) / 256, 256, 0, stream>>>(ei + E, cnt, E);
    k_blocksum<<<NB, 256, 0, stream>>>(cnt, bsums, N);
    k_scan_bsums<<<1, 256, 0, stream>>>(bsums, NB);
    k_scan_final<<<NB, 256, 0, stream>>>(cnt, bsums, rowptr, dinv, N, E);
    k_scatter<<<(E + 255) / 256, 256, 0, stream>>>(ei, cnt, dinv, csr, edat, E);
    k_w2cast<<<64, 256, 0, stream>>>(W2, W2b);
    k_w1cast<<<64, 256, 0, stream>>>(W1, W1t);
    k_wcat<<<64, 256, 0, stream>>>(Wq, Wk, Wv, Ws, Wcat);

    k_gemm1<<<(N + 15) / 16, 256, 0, stream>>>(x, W1t, xw1b, N);
    k_agg1<<<(N + 3) / 4, 256, 0, stream>>>(xw1b, edat, rowptr, dinv, b1, B, N);
    k_lin_qkvs<<<(N + 15) / 16, 256, 0, stream>>>(B, Wcat, bq, bk, bv, bs, kvb, h2b, N);
    k_attn<<<(N + 3) / 4, 256, 0, stream>>>(B, kvb, csr, rowptr, h2b, N);
    k_agg2gemm2<<<(N + 15) / 16, 256, 0, stream>>>(h2b, edat, rowptr, dinv, W2b, b2, out, N);
}

// Round 13
// 432.661 us; speedup vs baseline: 2.9007x; 1.0610x over previous
//
#include <hip/hip_runtime.h>
#include <hip/hip_bf16.h>

typedef unsigned short u16;
typedef unsigned int u32;

__device__ __forceinline__ float bl(u32 u) { union { u32 i; float f; } c; c.i = u << 16; return c.f; }
__device__ __forceinline__ float bh(u32 u) { union { u32 i; float f; } c; c.i = u & 0xffff0000u; return c.f; }
__device__ __forceinline__ u16 f2us(float f) {
    __hip_bfloat16 h = __float2bfloat16(f);
    return *reinterpret_cast<u16*>(&h);
}
__device__ __forceinline__ u32 pk2(float a, float b) {
    return (u32)f2us(a) | ((u32)f2us(b) << 16);
}
__device__ __forceinline__ void up8(uint4 u, float* f) {
    f[0] = bl(u.x); f[1] = bh(u.x); f[2] = bl(u.y); f[3] = bh(u.y);
    f[4] = bl(u.z); f[5] = bh(u.z); f[6] = bl(u.w); f[7] = bh(u.w);
}

typedef short bf16x8 __attribute__((ext_vector_type(8)));
typedef float f32x4 __attribute__((ext_vector_type(4)));

// ---------------- CSR build ----------------
__global__ void k_hist(const int* __restrict__ dst, int* __restrict__ cnt, int E) {
    int e = blockIdx.x * 256 + threadIdx.x;
    if (e < E) atomicAdd(&cnt[dst[e]], 1);
}

__global__ void k_blocksum(const int* __restrict__ cnt, int* __restrict__ bsums, int n) {
    int base = blockIdx.x * 1024;
    int t = threadIdx.x;
    int s = 0;
    for (int j = t; j < 1024; j += 256) { int i = base + j; if (i < n) s += cnt[i]; }
    __shared__ int red[256];
    red[t] = s; __syncthreads();
    for (int off = 128; off > 0; off >>= 1) { if (t < off) red[t] += red[t + off]; __syncthreads(); }
    if (t == 0) bsums[blockIdx.x] = red[0];
}

// parallel exclusive scan of bsums (nb <= 1024), one block of 256 threads
__global__ void k_scan_bsums(int* __restrict__ bsums, int nb) {
    int t = threadIdx.x;
    int i0 = t * 4;
    int v[4]; int s = 0;
    #pragma unroll
    for (int j = 0; j < 4; j++) { v[j] = (i0 + j < nb) ? bsums[i0 + j] : 0; s += v[j]; }
    __shared__ int sc[256];
    sc[t] = s; __syncthreads();
    int acc = s;
    for (int off = 1; off < 256; off <<= 1) {
        int add = (t >= off) ? sc[t - off] : 0;
        __syncthreads();
        acc += add; sc[t] = acc;
        __syncthreads();
    }
    int run = acc - s;
    #pragma unroll
    for (int j = 0; j < 4; j++) {
        if (i0 + j < nb) { bsums[i0 + j] = run; run += v[j]; }
    }
}

__global__ void k_scan_final(int* __restrict__ cnt, const int* __restrict__ bsums,
                             int* __restrict__ rowptr, float* __restrict__ dinv, int n, int E) {
    int base = blockIdx.x * 1024;
    int t = threadIdx.x;
    int i0 = base + t * 4;
    int v[4]; int s = 0;
    for (int j = 0; j < 4; j++) { int i = i0 + j; v[j] = (i < n) ? cnt[i] : 0; s += v[j]; }
    __shared__ int sc[256];
    sc[t] = s; __syncthreads();
    int acc = s;
    for (int off = 1; off < 256; off <<= 1) {
        int add = (t >= off) ? sc[t - off] : 0;
        __syncthreads();
        acc += add; sc[t] = acc;
        __syncthreads();
    }
    int run = acc - s + bsums[blockIdx.x];
    for (int j = 0; j < 4; j++) {
        int i = i0 + j;
        if (i < n) {
            rowptr[i] = run;
            dinv[i] = rsqrtf((float)(v[j] + 1));
            cnt[i] = run;   // cursor for scatter
            run += v[j];
        }
    }
    if (blockIdx.x == 0 && t == 0) rowptr[n] = E;
}

// single int2 record per edge: {src, wnorm} — one random cacheline per edge
__global__ void k_scatter(const int* __restrict__ ei, int* __restrict__ cursor,
                          const float* __restrict__ dinv,
                          int2* __restrict__ edat, int E) {
    int e = blockIdx.x * 256 + threadIdx.x;
    if (e < E) {
        int s = ei[e], d = ei[E + e];
        int pos = atomicAdd(&cursor[d], 1);
        edat[pos] = make_int2(s, __float_as_int(dinv[s] * dinv[d]));
    }
}

// ---------------- weight preconversions ----------------
__global__ void k_w2cast(const float* __restrict__ W2, u16* __restrict__ W2b) {
    int i = blockIdx.x * 256 + threadIdx.x;
    if (i < 64 * 256) W2b[i] = f2us(W2[i]);
}

// W1 [256][64] f32 -> W1t [64 cols][256 k] bf16
__global__ void k_w1cast(const float* __restrict__ W1, u16* __restrict__ W1t) {
    int i = blockIdx.x * 256 + threadIdx.x;   // i = col*256 + k
    if (i < 64 * 256) {
        int col = i >> 8, k = i & 255;
        W1t[i] = f2us(W1[k * 64 + col]);
    }
}

// Wq|Wk|Wv|Ws [64][64] f32 -> Wcat [256 outcols][64 k] bf16
__global__ void k_wcat(const float* __restrict__ Wq, const float* __restrict__ Wk,
                       const float* __restrict__ Wv, const float* __restrict__ Ws,
                       u16* __restrict__ Wcat) {
    int i = blockIdx.x * 256 + threadIdx.x;   // i = col*64 + k
    if (i < 256 * 64) {
        int col = i >> 6, k = i & 63;
        int m = col >> 6, mc = col & 63;
        const float* src = (m == 0) ? Wq : (m == 1) ? Wk : (m == 2) ? Wv : Ws;
        Wcat[i] = f2us(src[k * 64 + mc]);
    }
}

// ---------------- GEMM1 (MFMA): xw1b = bf16(x) @ W1 ; 16 nodes/block ----------------
__global__ __launch_bounds__(256) void k_gemm1(const float* __restrict__ x,
                                               const u16* __restrict__ W1t,
                                               u16* __restrict__ xw1b, int n) {
    __shared__ u16 xs[16][264];    // pitch 528B: 16B-aligned frags, 2-way bank alias only
    int t = threadIdx.x, w = t >> 6, l = t & 63;
    int base = blockIdx.x * 16;
    // stage x tile -> bf16
    int row = t >> 4, seg = t & 15;
    int node = base + row;
    const float4* src = (const float4*)(x + (size_t)(node < n ? node : n - 1) * 256 + seg * 16);
    float4 f0 = src[0], f1 = src[1], f2 = src[2], f3 = src[3];
    uint4 o0, o1;
    o0.x = pk2(f0.x, f0.y); o0.y = pk2(f0.z, f0.w);
    o0.z = pk2(f1.x, f1.y); o0.w = pk2(f1.z, f1.w);
    o1.x = pk2(f2.x, f2.y); o1.y = pk2(f2.z, f2.w);
    o1.z = pk2(f3.x, f3.y); o1.w = pk2(f3.z, f3.w);
    u16* dst = &xs[row][seg * 16];
    *(uint4*)dst = o0; *(uint4*)(dst + 8) = o1;
    __syncthreads();
    int c = l & 15, kg = l >> 4;
    int col = w * 16 + c;
    f32x4 acc = {0.f, 0.f, 0.f, 0.f};
    #pragma unroll
    for (int kk = 0; kk < 8; kk++) {
        bf16x8 a = *(const bf16x8*)&xs[c][kk * 32 + kg * 8];
        bf16x8 b = *(const bf16x8*)&W1t[(size_t)col * 256 + kk * 32 + kg * 8];
        acc = __builtin_amdgcn_mfma_f32_16x16x32_bf16(a, b, acc, 0, 0, 0);
    }
    #pragma unroll
    for (int r = 0; r < 4; r++) {
        int nd = base + kg * 4 + r;
        if (nd < n) xw1b[(size_t)nd * 64 + col] = f2us(acc[r]);
    }
}

// ------- GCN1 aggregate: h1 = relu(Anorm*xw1 + b1) -> B (f32). 8x8 groups, 16 edges in flight. -------
__global__ __launch_bounds__(256) void k_agg1(const u16* __restrict__ xw1b,
                                              const int2* __restrict__ edat,
                                              const int* __restrict__ rowptr,
                                              const float* __restrict__ dinv,
                                              const float* __restrict__ b1,
                                              float* __restrict__ B, int n) {
    int t = threadIdx.x;
    int w = t >> 6, l = t & 63, g = l >> 3, li = l & 7;
    int node = blockIdx.x * 4 + w;
    if (node >= n) return;
    int beg = rowptr[node], end = rowptr[node + 1];
    float a0[8], a1[8];
    #pragma unroll
    for (int j = 0; j < 8; j++) { a0[j] = 0.f; a1[j] = 0.f; }
    for (int e0 = beg; e0 < end; e0 += 16) {
        int eA = e0 + g, eB = e0 + 8 + g;
        bool vA = (eA < end), vB = (eB < end);
        int2 dA = vA ? edat[eA] : make_int2(0, 0);
        int2 dB = vB ? edat[eB] : make_int2(0, 0);
        uint4 uA = *(const uint4*)(xw1b + (size_t)dA.x * 64 + li * 8);
        uint4 uB = *(const uint4*)(xw1b + (size_t)dB.x * 64 + li * 8);
        float wA = __int_as_float(dA.y), wB = __int_as_float(dB.y);
        float fA[8]; up8(uA, fA);
        float fB[8]; up8(uB, fB);
        #pragma unroll
        for (int j = 0; j < 8; j++) { a0[j] += fA[j] * wA; a1[j] += fB[j] * wB; }
    }
    #pragma unroll
    for (int j = 0; j < 8; j++) a0[j] += a1[j];
    #pragma unroll
    for (int off = 8; off <= 32; off <<= 1)
        #pragma unroll
        for (int j = 0; j < 8; j++) a0[j] += __shfl_xor(a0[j], off);
    if (g == 0) {
        float di = dinv[node], di2 = di * di;
        uint4 u = *(const uint4*)(xw1b + (size_t)node * 64 + li * 8);
        float sf[8]; up8(u, sf);
        float4 bv0 = *(const float4*)(b1 + li * 8);
        float4 bv1 = *(const float4*)(b1 + li * 8 + 4);
        float bb[8] = {bv0.x, bv0.y, bv0.z, bv0.w, bv1.x, bv1.y, bv1.z, bv1.w};
        float r[8];
        #pragma unroll
        for (int j = 0; j < 8; j++) r[j] = fmaxf(a0[j] + sf[j] * di2 + bb[j], 0.f);
        float* dst = B + (size_t)node * 64 + li * 8;
        *(float4*)dst = make_float4(r[0], r[1], r[2], r[3]);
        *(float4*)(dst + 4) = make_float4(r[4], r[5], r[6], r[7]);
    }
}

// ------- lin_qkvs (MFMA): [q|k|v|s] = h1 @ Wcat; q->B f32 in-place, k/v->kvb, s->h2b -------
__global__ __launch_bounds__(256) void k_lin_qkvs(float* __restrict__ B,
                                                  const u16* __restrict__ Wcat,
                                                  const float* __restrict__ bq, const float* __restrict__ bk,
                                                  const float* __restrict__ bv, const float* __restrict__ bs,
                                                  u16* __restrict__ kvb, u16* __restrict__ h2b, int n) {
    __shared__ u16 hs[16][72];    // pitch 144B: 16B-aligned frags
    int t = threadIdx.x, w = t >> 6, l = t & 63;
    int base = blockIdx.x * 16;
    int row = t >> 4, q4 = t & 15;
    int node = base + row;
    if (node < n) {
        float4 f = *(const float4*)(B + (size_t)node * 64 + q4 * 4);
        uint2 o; o.x = pk2(f.x, f.y); o.y = pk2(f.z, f.w);
        *(uint2*)&hs[row][q4 * 4] = o;
    }
    __syncthreads();
    int c = l & 15, kg = l >> 4;
    bf16x8 a0 = *(const bf16x8*)&hs[c][kg * 8];
    bf16x8 a1 = *(const bf16x8*)&hs[c][32 + kg * 8];
    #pragma unroll
    for (int ti = 0; ti < 4; ti++) {
        int col = (w * 4 + ti) * 16 + c;
        bf16x8 b0 = *(const bf16x8*)&Wcat[(size_t)col * 64 + kg * 8];
        bf16x8 b1 = *(const bf16x8*)&Wcat[(size_t)col * 64 + 32 + kg * 8];
        f32x4 acc = {0.f, 0.f, 0.f, 0.f};
        acc = __builtin_amdgcn_mfma_f32_16x16x32_bf16(a0, b0, acc, 0, 0, 0);
        acc = __builtin_amdgcn_mfma_f32_16x16x32_bf16(a1, b1, acc, 0, 0, 0);
        int m = col >> 6, mc = col & 63;
        float bias = ((m == 0) ? bq : (m == 1) ? bk : (m == 2) ? bv : bs)[mc];
        #pragma unroll
        for (int r = 0; r < 4; r++) {
            int nd = base + kg * 4 + r;
            if (nd < n) {
                float v = acc[r] + bias;
                if (m == 0)      B[(size_t)nd * 64 + mc] = v;          // q (f32)
                else if (m == 1) kvb[(size_t)nd * 128 + mc] = f2us(v); // k
                else if (m == 2) kvb[(size_t)nd * 128 + 64 + mc] = f2us(v); // v
                else             h2b[(size_t)nd * 64 + mc] = f2us(v);  // skip
            }
        }
    }
}

// ------- attention: warp/node, 8x8 groups, 16 edges in flight (dual softmax state) -------
__global__ __launch_bounds__(256) void k_attn(const float* __restrict__ B,
                                              const u16* __restrict__ kvb,
                                              const int2* __restrict__ edat,
                                              const int* __restrict__ rowptr,
                                              u16* __restrict__ h2b, int n) {
    int t = threadIdx.x;
    int w = t >> 6, l = t & 63, g = l >> 3, li = l & 7;
    int node = blockIdx.x * 4 + w;
    if (node >= n) return;
    const float* qp = B + (size_t)node * 64 + li * 8;
    float4 qa = *(const float4*)qp;
    float4 qb = *(const float4*)(qp + 4);
    float q[8] = {qa.x, qa.y, qa.z, qa.w, qb.x, qb.y, qb.z, qb.w};
    int beg = rowptr[node], end = rowptr[node + 1];
    float mA = -1e30f, denA = 0.f, mB = -1e30f, denB = 0.f;
    float accA[8], accB[8];
    #pragma unroll
    for (int j = 0; j < 8; j++) { accA[j] = 0.f; accB[j] = 0.f; }
    for (int e0 = beg; e0 < end; e0 += 16) {
        int eA = e0 + g, eB = e0 + 8 + g;
        bool vA = (eA < end), vB = (eB < end);
        int sA = vA ? edat[eA].x : 0;
        int sB = vB ? edat[eB].x : 0;
        const u16* rowA = kvb + (size_t)sA * 128;
        const u16* rowB = kvb + (size_t)sB * 128;
        uint4 kuA = *(const uint4*)(rowA + li * 8);
        uint4 vuA = *(const uint4*)(rowA + 64 + li * 8);
        uint4 kuB = *(const uint4*)(rowB + li * 8);
        uint4 vuB = *(const uint4*)(rowB + 64 + li * 8);
        float kf[8], vf[8];
        // state A
        up8(kuA, kf); up8(vuA, vf);
        float dA = 0.f;
        #pragma unroll
        for (int j = 0; j < 8; j++) dA += q[j] * kf[j];
        dA += __shfl_xor(dA, 1);
        dA += __shfl_xor(dA, 2);
        dA += __shfl_xor(dA, 4);
        float logitA = vA ? dA * 0.125f : -1e30f;
        float nmA = fmaxf(mA, logitA);
        float rA = __expf(mA - nmA);
        float pA = vA ? __expf(logitA - nmA) : 0.f;
        denA = denA * rA + pA;
        #pragma unroll
        for (int j = 0; j < 8; j++) accA[j] = accA[j] * rA + pA * vf[j];
        mA = nmA;
        // state B
        up8(kuB, kf); up8(vuB, vf);
        float dB = 0.f;
        #pragma unroll
        for (int j = 0; j < 8; j++) dB += q[j] * kf[j];
        dB += __shfl_xor(dB, 1);
        dB += __shfl_xor(dB, 2);
        dB += __shfl_xor(dB, 4);
        float logitB = vB ? dB * 0.125f : -1e30f;
        float nmB = fmaxf(mB, logitB);
        float rB = __expf(mB - nmB);
        float pB = vB ? __expf(logitB - nmB) : 0.f;
        denB = denB * rB + pB;
        #pragma unroll
        for (int j = 0; j < 8; j++) accB[j] = accB[j] * rB + pB * vf[j];
        mB = nmB;
    }
    // merge A,B
    float m = fmaxf(mA, mB);
    float rA = __expf(mA - m), rB = __expf(mB - m);
    float den = denA * rA + denB * rB;
    float acc[8];
    #pragma unroll
    for (int j = 0; j < 8; j++) acc[j] = accA[j] * rA + accB[j] * rB;
    // merge 8 group states: butterfly xor 8,16,32
    #pragma unroll
    for (int off = 8; off <= 32; off <<= 1) {
        float mo = __shfl_xor(m, off);
        float deno = __shfl_xor(den, off);
        float nm = fmaxf(m, mo);
        float r = __expf(m - nm), ro = __expf(mo - nm);
        den = den * r + deno * ro;
        #pragma unroll
        for (int j = 0; j < 8; j++) {
            float ao = __shfl_xor(acc[j], off);
            acc[j] = acc[j] * r + ao * ro;
        }
        m = nm;
    }
    if (g == 0) {
        float inv = (den > 0.f) ? 1.f / den : 0.f;
        u16* hp = h2b + (size_t)node * 64 + li * 8;
        uint4 su = *(const uint4*)hp;    // skip pre-stored by lin_qkvs
        float sk[8]; up8(su, sk);
        float o[8];
        #pragma unroll
        for (int j = 0; j < 8; j++) o[j] = acc[j] * inv + sk[j];
        uint4 ou;
        ou.x = pk2(o[0], o[1]); ou.y = pk2(o[2], o[3]);
        ou.z = pk2(o[4], o[5]); ou.w = pk2(o[6], o[7]);
        *(uint4*)hp = ou;
    }
}

// ------- fused GCN2 aggregate + MFMA GEMM2: out = (Anorm*h2) @ W2 + b2 -------
__global__ __launch_bounds__(256) void k_agg2gemm2(const u16* __restrict__ h2b,
                                                   const int2* __restrict__ edat,
                                                   const int* __restrict__ rowptr,
                                                   const float* __restrict__ dinv,
                                                   const u16* __restrict__ W2b,
                                                   const float* __restrict__ b2,
                                                   float* __restrict__ out, int n) {
    __shared__ u16 ag[16][72];   // bf16 tile, padded pitch (144B rows, 16B-aligned frags)
    int t = threadIdx.x, w = t >> 6, l = t & 63, g = l >> 3, li = l & 7;
    int base = blockIdx.x * 16;
    for (int i = w; i < 16; i += 4) {
        int node = base + i;
        float a0[8], a1[8];
        #pragma unroll
        for (int j = 0; j < 8; j++) { a0[j] = 0.f; a1[j] = 0.f; }
        if (node < n) {
            int beg = rowptr[node], end = rowptr[node + 1];
            for (int e0 = beg; e0 < end; e0 += 16) {
                int eA = e0 + g, eB = e0 + 8 + g;
                bool vA = (eA < end), vB = (eB < end);
                int2 dA = vA ? edat[eA] : make_int2(0, 0);
                int2 dB = vB ? edat[eB] : make_int2(0, 0);
                uint4 uA = *(const uint4*)(h2b + (size_t)dA.x * 64 + li * 8);
                uint4 uB = *(const uint4*)(h2b + (size_t)dB.x * 64 + li * 8);
                float wA = __int_as_float(dA.y), wB = __int_as_float(dB.y);
                float fA[8]; up8(uA, fA);
                float fB[8]; up8(uB, fB);
                #pragma unroll
                for (int j = 0; j < 8; j++) { a0[j] += fA[j] * wA; a1[j] += fB[j] * wB; }
            }
        }
        #pragma unroll
        for (int j = 0; j < 8; j++) a0[j] += a1[j];
        #pragma unroll
        for (int off = 8; off <= 32; off <<= 1)
            #pragma unroll
            for (int j = 0; j < 8; j++) a0[j] += __shfl_xor(a0[j], off);
        if (g == 0) {
            if (node < n) {
                float di = dinv[node], di2 = di * di;
                uint4 u = *(const uint4*)(h2b + (size_t)node * 64 + li * 8);
                float sf[8]; up8(u, sf);
                #pragma unroll
                for (int j = 0; j < 8; j++) a0[j] += sf[j] * di2;
            }
            uint4 ou;
            ou.x = pk2(a0[0], a0[1]); ou.y = pk2(a0[2], a0[3]);
            ou.z = pk2(a0[4], a0[5]); ou.w = pk2(a0[6], a0[7]);
            *(uint4*)&ag[i][li * 8] = ou;
        }
    }
    __syncthreads();
    // ---- MFMA phase: C[16 x 256] = ag[16 x 64] @ W2b[64 x 256], f32 out + bias ----
    int c = l & 15;           // A-row / B-col / D-col
    int kg = l >> 4;          // k-group 0..3
    bf16x8 alo = *(const bf16x8*)&ag[c][kg * 8];
    bf16x8 ahi = *(const bf16x8*)&ag[c][32 + kg * 8];
    #pragma unroll
    for (int ti = 0; ti < 4; ti++) {
        int ct = w * 4 + ti;
        int col = ct * 16 + c;
        bf16x8 blo, bhi;
        #pragma unroll
        for (int j = 0; j < 8; j++) {
            blo[j] = (short)W2b[(kg * 8 + j) * 256 + col];
            bhi[j] = (short)W2b[(32 + kg * 8 + j) * 256 + col];
        }
        f32x4 acc = {0.f, 0.f, 0.f, 0.f};
        acc = __builtin_amdgcn_mfma_f32_16x16x32_bf16(alo, blo, acc, 0, 0, 0);
        acc = __builtin_amdgcn_mfma_f32_16x16x32_bf16(ahi, bhi, acc, 0, 0, 0);
        float bias = b2[col];
        #pragma unroll
        for (int r = 0; r < 4; r++) {
            int node = base + kg * 4 + r;
            if (node < n) out[(size_t)node * 256 + col] = acc[r] + bias;
        }
    }
}

extern "C" void kernel_launch(void* const* d_in, const int* in_sizes, int n_in,
                              void* d_out, int out_size, void* d_ws, size_t ws_size,
                              hipStream_t stream) {
    const float* x  = (const float*)d_in[0];
    const int*   ei = (const int*)d_in[1];
    const float* W1 = (const float*)d_in[2];
    const float* b1 = (const float*)d_in[3];
    const float* Wq = (const float*)d_in[4];
    const float* bq = (const float*)d_in[5];
    const float* Wk = (const float*)d_in[6];
    const float* bk = (const float*)d_in[7];
    const float* Wv = (const float*)d_in[8];
    const float* bv = (const float*)d_in[9];
    const float* Ws = (const float*)d_in[10];
    const float* bs = (const float*)d_in[11];
    const float* W2 = (const float*)d_in[12];
    const float* b2 = (const float*)d_in[13];
    float* out = (float*)d_out;

    const int N = in_sizes[0] / 256;
    const int E = in_sizes[1] / 2;

    // d_out staging (all dead before k_agg2gemm2 rewrites out):
    //   kvb  bf16 [N][128] (K||V)      25.6 MB
    //   xw1b bf16 [N][64]              12.8 MB
    //   B    f32  [N][64] (h1 then q)  25.6 MB   -> 64 MB <= out 100 MB
    char* ob = (char*)d_out;
    u16*   kvb  = (u16*)ob;
    u16*   xw1b = (u16*)(ob + (size_t)N * 128 * 2);
    float* B    = (float*)(ob + (size_t)N * 128 * 2 + (size_t)N * 64 * 2);

    // d_ws (~27 MB): CSR machinery + packed edge data + h2 (bf16) + weight casts
    char* p = (char*)d_ws;
    auto alloc = [&](size_t bytes) { char* r = p; p += (bytes + 255) & ~(size_t)255; return r; };
    int*   cnt    = (int*)alloc((size_t)N * 4);        // becomes scatter cursor
    int*   rowptr = (int*)alloc((size_t)(N + 1) * 4);
    int*   bsums  = (int*)alloc(4096);
    int2*  edat   = (int2*)alloc((size_t)E * 8);
    float* dinv   = (float*)alloc((size_t)N * 4);
    u16*   h2b    = (u16*)alloc((size_t)N * 64 * 2);
    u16*   W2b    = (u16*)alloc((size_t)64 * 256 * 2);
    u16*   W1t    = (u16*)alloc((size_t)64 * 256 * 2);
    u16*   Wcat   = (u16*)alloc((size_t)256 * 64 * 2);

    const int NB = (N + 1023) / 1024;

    hipMemsetAsync(cnt, 0, (size_t)N * 4, stream);
    k_hist<<<(E + 255) / 256, 256, 0, stream>>>(ei + E, cnt, E);
    k_blocksum<<<NB, 256, 0, stream>>>(cnt, bsums, N);
    k_scan_bsums<<<1, 256, 0, stream>>>(bsums, NB);
    k_scan_final<<<NB, 256, 0, stream>>>(cnt, bsums, rowptr, dinv, N, E);
    k_scatter<<<(E + 255) / 256, 256, 0, stream>>>(ei, cnt, dinv, edat, E);
    k_w2cast<<<64, 256, 0, stream>>>(W2, W2b);
    k_w1cast<<<64, 256, 0, stream>>>(W1, W1t);
    k_wcat<<<64, 256, 0, stream>>>(Wq, Wk, Wv, Ws, Wcat);

    k_gemm1<<<(N + 15) / 16, 256, 0, stream>>>(x, W1t, xw1b, N);
    k_agg1<<<(N + 3) / 4, 256, 0, stream>>>(xw1b, edat, rowptr, dinv, b1, B, N);
    k_lin_qkvs<<<(N + 15) / 16, 256, 0, stream>>>(B, Wcat, bq, bk, bv, bs, kvb, h2b, N);
    k_attn<<<(N + 3) / 4, 256, 0, stream>>>(B, kvb, edat, rowptr, h2b, N);
    k_agg2gemm2<<<(N + 15) / 16, 256, 0, stream>>>(h2b, edat, rowptr, dinv, W2b, b2, out, N);
}

// Round 14
// 423.265 us; speedup vs baseline: 2.9651x; 1.0222x over previous
//
#include <hip/hip_runtime.h>
#include <hip/hip_bf16.h>

typedef unsigned short u16;
typedef unsigned int u32;

__device__ __forceinline__ float bl(u32 u) { union { u32 i; float f; } c; c.i = u << 16; return c.f; }
__device__ __forceinline__ float bh(u32 u) { union { u32 i; float f; } c; c.i = u & 0xffff0000u; return c.f; }
__device__ __forceinline__ u16 f2us(float f) {
    __hip_bfloat16 h = __float2bfloat16(f);
    return *reinterpret_cast<u16*>(&h);
}
__device__ __forceinline__ u32 pk2(float a, float b) {
    return (u32)f2us(a) | ((u32)f2us(b) << 16);
}
__device__ __forceinline__ void up8(uint4 u, float* f) {
    f[0] = bl(u.x); f[1] = bh(u.x); f[2] = bl(u.y); f[3] = bh(u.y);
    f[4] = bl(u.z); f[5] = bh(u.z); f[6] = bl(u.w); f[7] = bh(u.w);
}

typedef short bf16x8 __attribute__((ext_vector_type(8)));
typedef float f32x4 __attribute__((ext_vector_type(4)));

// ---------------- CSR build ----------------
__global__ void k_hist(const int* __restrict__ dst, int* __restrict__ cnt, int E) {
    int e = blockIdx.x * 256 + threadIdx.x;
    if (e < E) atomicAdd(&cnt[dst[e]], 1);
}

__global__ void k_blocksum(const int* __restrict__ cnt, int* __restrict__ bsums, int n) {
    int base = blockIdx.x * 1024;
    int t = threadIdx.x;
    int s = 0;
    for (int j = t; j < 1024; j += 256) { int i = base + j; if (i < n) s += cnt[i]; }
    __shared__ int red[256];
    red[t] = s; __syncthreads();
    for (int off = 128; off > 0; off >>= 1) { if (t < off) red[t] += red[t + off]; __syncthreads(); }
    if (t == 0) bsums[blockIdx.x] = red[0];
}

// parallel exclusive scan of bsums (nb <= 1024), one block of 256 threads
__global__ void k_scan_bsums(int* __restrict__ bsums, int nb) {
    int t = threadIdx.x;
    int i0 = t * 4;
    int v[4]; int s = 0;
    #pragma unroll
    for (int j = 0; j < 4; j++) { v[j] = (i0 + j < nb) ? bsums[i0 + j] : 0; s += v[j]; }
    __shared__ int sc[256];
    sc[t] = s; __syncthreads();
    int acc = s;
    for (int off = 1; off < 256; off <<= 1) {
        int add = (t >= off) ? sc[t - off] : 0;
        __syncthreads();
        acc += add; sc[t] = acc;
        __syncthreads();
    }
    int run = acc - s;
    #pragma unroll
    for (int j = 0; j < 4; j++) {
        if (i0 + j < nb) { bsums[i0 + j] = run; run += v[j]; }
    }
}

__global__ void k_scan_final(int* __restrict__ cnt, const int* __restrict__ bsums,
                             int* __restrict__ rowptr, float* __restrict__ dinv, int n, int E) {
    int base = blockIdx.x * 1024;
    int t = threadIdx.x;
    int i0 = base + t * 4;
    int v[4]; int s = 0;
    for (int j = 0; j < 4; j++) { int i = i0 + j; v[j] = (i < n) ? cnt[i] : 0; s += v[j]; }
    __shared__ int sc[256];
    sc[t] = s; __syncthreads();
    int acc = s;
    for (int off = 1; off < 256; off <<= 1) {
        int add = (t >= off) ? sc[t - off] : 0;
        __syncthreads();
        acc += add; sc[t] = acc;
        __syncthreads();
    }
    int run = acc - s + bsums[blockIdx.x];
    for (int j = 0; j < 4; j++) {
        int i = i0 + j;
        if (i < n) {
            rowptr[i] = run;
            dinv[i] = rsqrtf((float)(v[j] + 1));
            cnt[i] = run;   // cursor for scatter
            run += v[j];
        }
    }
    if (blockIdx.x == 0 && t == 0) rowptr[n] = E;
}

// XCD-bucketed scatter: dst-space split into 8 ranges; block with (blockIdx&7)==x
// handles range x only -> each XCD's L2 owns a 1.6MB edat window, lines merge
// before writeback (fixes the E*64B write amplification). Perf heuristic only:
// wrong XCD mapping degrades speed, never correctness.
__global__ void k_scatter(const int* __restrict__ ei, int* __restrict__ cursor,
                          const float* __restrict__ dinv,
                          int2* __restrict__ edat, int E, int N) {
    int xcd = blockIdx.x & 7;
    int chunk = blockIdx.x >> 3;
    int nchunks = gridDim.x >> 3;
    int per = (E + nchunks - 1) / nchunks;
    int beg = chunk * per;
    int end = min(beg + per, E);
    int lo = (int)(((long long)N * xcd) >> 3);
    int hi = (int)(((long long)N * (xcd + 1)) >> 3);
    for (int e = beg + (int)threadIdx.x; e < end; e += 256) {
        int d = ei[E + e];
        if (d >= lo && d < hi) {
            int s = ei[e];
            int pos = atomicAdd(&cursor[d], 1);
            edat[pos] = make_int2(s, __float_as_int(dinv[s] * dinv[d]));
        }
    }
}

// ---------------- fused weight preconversion (one launch) ----------------
// W2b[64*256] direct; W1t[64 cols][256 k]; Wcat[256 cols][64 k]
__global__ void k_wprep(const float* __restrict__ W1, const float* __restrict__ W2,
                        const float* __restrict__ Wq, const float* __restrict__ Wk,
                        const float* __restrict__ Wv, const float* __restrict__ Ws,
                        u16* __restrict__ W1t, u16* __restrict__ W2b, u16* __restrict__ Wcat) {
    int i = blockIdx.x * 256 + threadIdx.x;
    if (i < 16384) {
        W2b[i] = f2us(W2[i]);
    } else if (i < 32768) {
        int j = i - 16384; int col = j >> 8, k = j & 255;
        W1t[j] = f2us(W1[k * 64 + col]);
    } else if (i < 49152) {
        int j = i - 32768; int col = j >> 6, k = j & 63;
        int m = col >> 6, mc = col & 63;
        const float* src = (m == 0) ? Wq : (m == 1) ? Wk : (m == 2) ? Wv : Ws;
        Wcat[j] = f2us(src[k * 64 + mc]);
    }
}

// ---------------- GEMM1 (MFMA): xw1b = bf16(x) @ W1 ; 16 nodes/block ----------------
__global__ __launch_bounds__(256) void k_gemm1(const float* __restrict__ x,
                                               const u16* __restrict__ W1t,
                                               u16* __restrict__ xw1b, int n) {
    __shared__ u16 xs[16][264];    // pitch 528B: 16B-aligned frags, 2-way bank alias only
    int t = threadIdx.x, w = t >> 6, l = t & 63;
    int base = blockIdx.x * 16;
    // stage x tile -> bf16
    int row = t >> 4, seg = t & 15;
    int node = base + row;
    const float4* src = (const float4*)(x + (size_t)(node < n ? node : n - 1) * 256 + seg * 16);
    float4 f0 = src[0], f1 = src[1], f2 = src[2], f3 = src[3];
    uint4 o0, o1;
    o0.x = pk2(f0.x, f0.y); o0.y = pk2(f0.z, f0.w);
    o0.z = pk2(f1.x, f1.y); o0.w = pk2(f1.z, f1.w);
    o1.x = pk2(f2.x, f2.y); o1.y = pk2(f2.z, f2.w);
    o1.z = pk2(f3.x, f3.y); o1.w = pk2(f3.z, f3.w);
    u16* dst = &xs[row][seg * 16];
    *(uint4*)dst = o0; *(uint4*)(dst + 8) = o1;
    __syncthreads();
    int c = l & 15, kg = l >> 4;
    int col = w * 16 + c;
    f32x4 acc = {0.f, 0.f, 0.f, 0.f};
    #pragma unroll
    for (int kk = 0; kk < 8; kk++) {
        bf16x8 a = *(const bf16x8*)&xs[c][kk * 32 + kg * 8];
        bf16x8 b = *(const bf16x8*)&W1t[(size_t)col * 256 + kk * 32 + kg * 8];
        acc = __builtin_amdgcn_mfma_f32_16x16x32_bf16(a, b, acc, 0, 0, 0);
    }
    #pragma unroll
    for (int r = 0; r < 4; r++) {
        int nd = base + kg * 4 + r;
        if (nd < n) xw1b[(size_t)nd * 64 + col] = f2us(acc[r]);
    }
}

// ------- GCN1 aggregate: h1 = relu(Anorm*xw1 + b1) -> B (f32). 8x8 groups, 16 edges in flight. -------
__global__ __launch_bounds__(256) void k_agg1(const u16* __restrict__ xw1b,
                                              const int2* __restrict__ edat,
                                              const int* __restrict__ rowptr,
                                              const float* __restrict__ dinv,
                                              const float* __restrict__ b1,
                                              float* __restrict__ B, int n) {
    int t = threadIdx.x;
    int w = t >> 6, l = t & 63, g = l >> 3, li = l & 7;
    int node = blockIdx.x * 4 + w;
    if (node >= n) return;
    int beg = rowptr[node], end = rowptr[node + 1];
    float a0[8], a1[8];
    #pragma unroll
    for (int j = 0; j < 8; j++) { a0[j] = 0.f; a1[j] = 0.f; }
    for (int e0 = beg; e0 < end; e0 += 16) {
        int eA = e0 + g, eB = e0 + 8 + g;
        bool vA = (eA < end), vB = (eB < end);
        int2 dA = vA ? edat[eA] : make_int2(0, 0);
        int2 dB = vB ? edat[eB] : make_int2(0, 0);
        uint4 uA = *(const uint4*)(xw1b + (size_t)dA.x * 64 + li * 8);
        uint4 uB = *(const uint4*)(xw1b + (size_t)dB.x * 64 + li * 8);
        float wA = __int_as_float(dA.y), wB = __int_as_float(dB.y);
        float fA[8]; up8(uA, fA);
        float fB[8]; up8(uB, fB);
        #pragma unroll
        for (int j = 0; j < 8; j++) { a0[j] += fA[j] * wA; a1[j] += fB[j] * wB; }
    }
    #pragma unroll
    for (int j = 0; j < 8; j++) a0[j] += a1[j];
    #pragma unroll
    for (int off = 8; off <= 32; off <<= 1)
        #pragma unroll
        for (int j = 0; j < 8; j++) a0[j] += __shfl_xor(a0[j], off);
    if (g == 0) {
        float di = dinv[node], di2 = di * di;
        uint4 u = *(const uint4*)(xw1b + (size_t)node * 64 + li * 8);
        float sf[8]; up8(u, sf);
        float4 bv0 = *(const float4*)(b1 + li * 8);
        float4 bv1 = *(const float4*)(b1 + li * 8 + 4);
        float bb[8] = {bv0.x, bv0.y, bv0.z, bv0.w, bv1.x, bv1.y, bv1.z, bv1.w};
        float r[8];
        #pragma unroll
        for (int j = 0; j < 8; j++) r[j] = fmaxf(a0[j] + sf[j] * di2 + bb[j], 0.f);
        float* dst = B + (size_t)node * 64 + li * 8;
        *(float4*)dst = make_float4(r[0], r[1], r[2], r[3]);
        *(float4*)(dst + 4) = make_float4(r[4], r[5], r[6], r[7]);
    }
}

// ------- lin_qkvs (MFMA): [q|k|v|s] = h1 @ Wcat; q->B f32 in-place, k/v->kvb, s->h2b -------
__global__ __launch_bounds__(256) void k_lin_qkvs(float* __restrict__ B,
                                                  const u16* __restrict__ Wcat,
                                                  const float* __restrict__ bq, const float* __restrict__ bk,
                                                  const float* __restrict__ bv, const float* __restrict__ bs,
                                                  u16* __restrict__ kvb, u16* __restrict__ h2b, int n) {
    __shared__ u16 hs[16][72];    // pitch 144B: 16B-aligned frags
    int t = threadIdx.x, w = t >> 6, l = t & 63;
    int base = blockIdx.x * 16;
    int row = t >> 4, q4 = t & 15;
    int node = base + row;
    if (node < n) {
        float4 f = *(const float4*)(B + (size_t)node * 64 + q4 * 4);
        uint2 o; o.x = pk2(f.x, f.y); o.y = pk2(f.z, f.w);
        *(uint2*)&hs[row][q4 * 4] = o;
    }
    __syncthreads();
    int c = l & 15, kg = l >> 4;
    bf16x8 a0 = *(const bf16x8*)&hs[c][kg * 8];
    bf16x8 a1 = *(const bf16x8*)&hs[c][32 + kg * 8];
    #pragma unroll
    for (int ti = 0; ti < 4; ti++) {
        int col = (w * 4 + ti) * 16 + c;
        bf16x8 b0 = *(const bf16x8*)&Wcat[(size_t)col * 64 + kg * 8];
        bf16x8 b1 = *(const bf16x8*)&Wcat[(size_t)col * 64 + 32 + kg * 8];
        f32x4 acc = {0.f, 0.f, 0.f, 0.f};
        acc = __builtin_amdgcn_mfma_f32_16x16x32_bf16(a0, b0, acc, 0, 0, 0);
        acc = __builtin_amdgcn_mfma_f32_16x16x32_bf16(a1, b1, acc, 0, 0, 0);
        int m = col >> 6, mc = col & 63;
        float bias = ((m == 0) ? bq : (m == 1) ? bk : (m == 2) ? bv : bs)[mc];
        #pragma unroll
        for (int r = 0; r < 4; r++) {
            int nd = base + kg * 4 + r;
            if (nd < n) {
                float v = acc[r] + bias;
                if (m == 0)      B[(size_t)nd * 64 + mc] = v;          // q (f32)
                else if (m == 1) kvb[(size_t)nd * 128 + mc] = f2us(v); // k
                else if (m == 2) kvb[(size_t)nd * 128 + 64 + mc] = f2us(v); // v
                else             h2b[(size_t)nd * 64 + mc] = f2us(v);  // skip
            }
        }
    }
}

// ------- attention: warp/node, 8x8 groups, 16 edges in flight (dual softmax state) -------
__global__ __launch_bounds__(256) void k_attn(const float* __restrict__ B,
                                              const u16* __restrict__ kvb,
                                              const int2* __restrict__ edat,
                                              const int* __restrict__ rowptr,
                                              u16* __restrict__ h2b, int n) {
    int t = threadIdx.x;
    int w = t >> 6, l = t & 63, g = l >> 3, li = l & 7;
    int node = blockIdx.x * 4 + w;
    if (node >= n) return;
    const float* qp = B + (size_t)node * 64 + li * 8;
    float4 qa = *(const float4*)qp;
    float4 qb = *(const float4*)(qp + 4);
    float q[8] = {qa.x, qa.y, qa.z, qa.w, qb.x, qb.y, qb.z, qb.w};
    int beg = rowptr[node], end = rowptr[node + 1];
    float mA = -1e30f, denA = 0.f, mB = -1e30f, denB = 0.f;
    float accA[8], accB[8];
    #pragma unroll
    for (int j = 0; j < 8; j++) { accA[j] = 0.f; accB[j] = 0.f; }
    for (int e0 = beg; e0 < end; e0 += 16) {
        int eA = e0 + g, eB = e0 + 8 + g;
        bool vA = (eA < end), vB = (eB < end);
        int sA = vA ? edat[eA].x : 0;
        int sB = vB ? edat[eB].x : 0;
        const u16* rowA = kvb + (size_t)sA * 128;
        const u16* rowB = kvb + (size_t)sB * 128;
        uint4 kuA = *(const uint4*)(rowA + li * 8);
        uint4 vuA = *(const uint4*)(rowA + 64 + li * 8);
        uint4 kuB = *(const uint4*)(rowB + li * 8);
        uint4 vuB = *(const uint4*)(rowB + 64 + li * 8);
        float kf[8], vf[8];
        // state A
        up8(kuA, kf); up8(vuA, vf);
        float dA = 0.f;
        #pragma unroll
        for (int j = 0; j < 8; j++) dA += q[j] * kf[j];
        dA += __shfl_xor(dA, 1);
        dA += __shfl_xor(dA, 2);
        dA += __shfl_xor(dA, 4);
        float logitA = vA ? dA * 0.125f : -1e30f;
        float nmA = fmaxf(mA, logitA);
        float rA = __expf(mA - nmA);
        float pA = vA ? __expf(logitA - nmA) : 0.f;
        denA = denA * rA + pA;
        #pragma unroll
        for (int j = 0; j < 8; j++) accA[j] = accA[j] * rA + pA * vf[j];
        mA = nmA;
        // state B
        up8(kuB, kf); up8(vuB, vf);
        float dB = 0.f;
        #pragma unroll
        for (int j = 0; j < 8; j++) dB += q[j] * kf[j];
        dB += __shfl_xor(dB, 1);
        dB += __shfl_xor(dB, 2);
        dB += __shfl_xor(dB, 4);
        float logitB = vB ? dB * 0.125f : -1e30f;
        float nmB = fmaxf(mB, logitB);
        float rB = __expf(mB - nmB);
        float pB = vB ? __expf(logitB - nmB) : 0.f;
        denB = denB * rB + pB;
        #pragma unroll
        for (int j = 0; j < 8; j++) accB[j] = accB[j] * rB + pB * vf[j];
        mB = nmB;
    }
    // merge A,B
    float m = fmaxf(mA, mB);
    float rA = __expf(mA - m), rB = __expf(mB - m);
    float den = denA * rA + denB * rB;
    float acc[8];
    #pragma unroll
    for (int j = 0; j < 8; j++) acc[j] = accA[j] * rA + accB[j] * rB;
    // merge 8 group states: butterfly xor 8,16,32
    #pragma unroll
    for (int off = 8; off <= 32; off <<= 1) {
        float mo = __shfl_xor(m, off);
        float deno = __shfl_xor(den, off);
        float nm = fmaxf(m, mo);
        float r = __expf(m - nm), ro = __expf(mo - nm);
        den = den * r + deno * ro;
        #pragma unroll
        for (int j = 0; j < 8; j++) {
            float ao = __shfl_xor(acc[j], off);
            acc[j] = acc[j] * r + ao * ro;
        }
        m = nm;
    }
    if (g == 0) {
        float inv = (den > 0.f) ? 1.f / den : 0.f;
        u16* hp = h2b + (size_t)node * 64 + li * 8;
        uint4 su = *(const uint4*)hp;    // skip pre-stored by lin_qkvs
        float sk[8]; up8(su, sk);
        float o[8];
        #pragma unroll
        for (int j = 0; j < 8; j++) o[j] = acc[j] * inv + sk[j];
        uint4 ou;
        ou.x = pk2(o[0], o[1]); ou.y = pk2(o[2], o[3]);
        ou.z = pk2(o[4], o[5]); ou.w = pk2(o[6], o[7]);
        *(uint4*)hp = ou;
    }
}

// ------- fused GCN2 aggregate + MFMA GEMM2: out = (Anorm*h2) @ W2 + b2 -------
__global__ __launch_bounds__(256) void k_agg2gemm2(const u16* __restrict__ h2b,
                                                   const int2* __restrict__ edat,
                                                   const int* __restrict__ rowptr,
                                                   const float* __restrict__ dinv,
                                                   const u16* __restrict__ W2b,
                                                   const float* __restrict__ b2,
                                                   float* __restrict__ out, int n) {
    __shared__ u16 ag[16][72];   // bf16 tile, padded pitch (144B rows, 16B-aligned frags)
    int t = threadIdx.x, w = t >> 6, l = t & 63, g = l >> 3, li = l & 7;
    int base = blockIdx.x * 16;
    for (int i = w; i < 16; i += 4) {
        int node = base + i;
        float a0[8], a1[8];
        #pragma unroll
        for (int j = 0; j < 8; j++) { a0[j] = 0.f; a1[j] = 0.f; }
        if (node < n) {
            int beg = rowptr[node], end = rowptr[node + 1];
            for (int e0 = beg; e0 < end; e0 += 16) {
                int eA = e0 + g, eB = e0 + 8 + g;
                bool vA = (eA < end), vB = (eB < end);
                int2 dA = vA ? edat[eA] : make_int2(0, 0);
                int2 dB = vB ? edat[eB] : make_int2(0, 0);
                uint4 uA = *(const uint4*)(h2b + (size_t)dA.x * 64 + li * 8);
                uint4 uB = *(const uint4*)(h2b + (size_t)dB.x * 64 + li * 8);
                float wA = __int_as_float(dA.y), wB = __int_as_float(dB.y);
                float fA[8]; up8(uA, fA);
                float fB[8]; up8(uB, fB);
                #pragma unroll
                for (int j = 0; j < 8; j++) { a0[j] += fA[j] * wA; a1[j] += fB[j] * wB; }
            }
        }
        #pragma unroll
        for (int j = 0; j < 8; j++) a0[j] += a1[j];
        #pragma unroll
        for (int off = 8; off <= 32; off <<= 1)
            #pragma unroll
            for (int j = 0; j < 8; j++) a0[j] += __shfl_xor(a0[j], off);
        if (g == 0) {
            if (node < n) {
                float di = dinv[node], di2 = di * di;
                uint4 u = *(const uint4*)(h2b + (size_t)node * 64 + li * 8);
                float sf[8]; up8(u, sf);
                #pragma unroll
                for (int j = 0; j < 8; j++) a0[j] += sf[j] * di2;
            }
            uint4 ou;
            ou.x = pk2(a0[0], a0[1]); ou.y = pk2(a0[2], a0[3]);
            ou.z = pk2(a0[4], a0[5]); ou.w = pk2(a0[6], a0[7]);
            *(uint4*)&ag[i][li * 8] = ou;
        }
    }
    __syncthreads();
    // ---- MFMA phase: C[16 x 256] = ag[16 x 64] @ W2b[64 x 256], f32 out + bias ----
    int c = l & 15;           // A-row / B-col / D-col
    int kg = l >> 4;          // k-group 0..3
    bf16x8 alo = *(const bf16x8*)&ag[c][kg * 8];
    bf16x8 ahi = *(const bf16x8*)&ag[c][32 + kg * 8];
    #pragma unroll
    for (int ti = 0; ti < 4; ti++) {
        int ct = w * 4 + ti;
        int col = ct * 16 + c;
        bf16x8 blo, bhi;
        #pragma unroll
        for (int j = 0; j < 8; j++) {
            blo[j] = (short)W2b[(kg * 8 + j) * 256 + col];
            bhi[j] = (short)W2b[(32 + kg * 8 + j) * 256 + col];
        }
        f32x4 acc = {0.f, 0.f, 0.f, 0.f};
        acc = __builtin_amdgcn_mfma_f32_16x16x32_bf16(alo, blo, acc, 0, 0, 0);
        acc = __builtin_amdgcn_mfma_f32_16x16x32_bf16(ahi, bhi, acc, 0, 0, 0);
        float bias = b2[col];
        #pragma unroll
        for (int r = 0; r < 4; r++) {
            int node = base + kg * 4 + r;
            if (node < n) out[(size_t)node * 256 + col] = acc[r] + bias;
        }
    }
}

extern "C" void kernel_launch(void* const* d_in, const int* in_sizes, int n_in,
                              void* d_out, int out_size, void* d_ws, size_t ws_size,
                              hipStream_t stream) {
    const float* x  = (const float*)d_in[0];
    const int*   ei = (const int*)d_in[1];
    const float* W1 = (const float*)d_in[2];
    const float* b1 = (const float*)d_in[3];
    const float* Wq = (const float*)d_in[4];
    const float* bq = (const float*)d_in[5];
    const float* Wk = (const float*)d_in[6];
    const float* bk = (const float*)d_in[7];
    const float* Wv = (const float*)d_in[8];
    const float* bv = (const float*)d_in[9];
    const float* Ws = (const float*)d_in[10];
    const float* bs = (const float*)d_in[11];
    const float* W2 = (const float*)d_in[12];
    const float* b2 = (const float*)d_in[13];
    float* out = (float*)d_out;

    const int N = in_sizes[0] / 256;
    const int E = in_sizes[1] / 2;

    // d_out staging (all dead before k_agg2gemm2 rewrites out):
    //   kvb  bf16 [N][128] (K||V)      25.6 MB
    //   xw1b bf16 [N][64]              12.8 MB
    //   B    f32  [N][64] (h1 then q)  25.6 MB   -> 64 MB <= out 100 MB
    char* ob = (char*)d_out;
    u16*   kvb  = (u16*)ob;
    u16*   xw1b = (u16*)(ob + (size_t)N * 128 * 2);
    float* B    = (float*)(ob + (size_t)N * 128 * 2 + (size_t)N * 64 * 2);

    // d_ws (~27 MB): CSR machinery + packed edge data + h2 (bf16) + weight casts
    char* p = (char*)d_ws;
    auto alloc = [&](size_t bytes) { char* r = p; p += (bytes + 255) & ~(size_t)255; return r; };
    int*   cnt    = (int*)alloc((size_t)N * 4);        // becomes scatter cursor
    int*   rowptr = (int*)alloc((size_t)(N + 1) * 4);
    int*   bsums  = (int*)alloc(4096);
    int2*  edat   = (int2*)alloc((size_t)E * 8);
    float* dinv   = (float*)alloc((size_t)N * 4);
    u16*   h2b    = (u16*)alloc((size_t)N * 64 * 2);
    u16*   W2b    = (u16*)alloc((size_t)64 * 256 * 2);
    u16*   W1t    = (u16*)alloc((size_t)64 * 256 * 2);
    u16*   Wcat   = (u16*)alloc((size_t)256 * 64 * 2);

    const int NB = (N + 1023) / 1024;

    hipMemsetAsync(cnt, 0, (size_t)N * 4, stream);
    k_hist<<<(E + 255) / 256, 256, 0, stream>>>(ei + E, cnt, E);
    k_blocksum<<<NB, 256, 0, stream>>>(cnt, bsums, N);
    k_scan_bsums<<<1, 256, 0, stream>>>(bsums, NB);
    k_scan_final<<<NB, 256, 0, stream>>>(cnt, bsums, rowptr, dinv, N, E);
    k_scatter<<<512 * 8, 256, 0, stream>>>(ei, cnt, dinv, edat, E, N);
    k_wprep<<<192, 256, 0, stream>>>(W1, W2, Wq, Wk, Wv, Ws, W1t, W2b, Wcat);

    k_gemm1<<<(N + 15) / 16, 256, 0, stream>>>(x, W1t, xw1b, N);
    k_agg1<<<(N + 3) / 4, 256, 0, stream>>>(xw1b, edat, rowptr, dinv, b1, B, N);
    k_lin_qkvs<<<(N + 15) / 16, 256, 0, stream>>>(B, Wcat, bq, bk, bv, bs, kvb, h2b, N);
    k_attn<<<(N + 3) / 4, 256, 0, stream>>>(B, kvb, edat, rowptr, h2b, N);
    k_agg2gemm2<<<(N + 15) / 16, 256, 0, stream>>>(h2b, edat, rowptr, dinv, W2b, b2, out, N);
}